// Round 4
// baseline (3104.841 us; speedup 1.0000x reference)
//
#include <hip/hip_runtime.h>
#include <math.h>

// Problem constants
#define Bc   16
#define Sc   1000
#define Dc   640
#define EMBc 128
#define Hc   8
#define HDc  80
#define Lc   6
#define DFFc 2048
#define NTOK (Bc * Sc)          // 16000

typedef __attribute__((ext_vector_type(8))) short short8;
typedef __attribute__((ext_vector_type(4))) float f32x4;

__device__ __forceinline__ float b2f(ushort u) {
    return __uint_as_float(((unsigned)u) << 16);
}
__device__ __forceinline__ ushort f2b(float f) {
    unsigned u = __float_as_uint(f);
    unsigned r = (u + 0x7fffu + ((u >> 16) & 1u)) >> 16;
    return (ushort)r;
}

#define GLL16(gp, lp) __builtin_amdgcn_global_load_lds( \
    (const __attribute__((address_space(1))) void*)(gp), \
    (__attribute__((address_space(3))) void*)(lp), 16, 0, 0)

// Property tables (PROP_TABLES constant in reference)
__constant__ float c_hydro[22]  = {1.8f,-4.5f,-3.5f,-3.5f,2.5f,-3.5f,-3.5f,-0.4f,-3.2f,4.5f,3.8f,-3.9f,1.9f,2.8f,-1.6f,-0.8f,-0.7f,-0.9f,-1.3f,4.2f,0.f,0.f};
__constant__ float c_charge[22] = {0.f,1.f,0.f,-1.f,0.f,0.f,-1.f,0.f,1.f,0.f,0.f,1.f,0.f,0.f,0.f,0.f,0.f,0.f,0.f,0.f,0.f,0.f};
__constant__ float c_vol[22]    = {88.6f,173.4f,114.1f,111.1f,108.5f,143.9f,138.4f,60.1f,153.2f,166.7f,166.7f,168.6f,162.9f,189.9f,112.7f,89.0f,116.1f,227.8f,193.6f,140.0f,0.f,100.f};

// ---------------------------------------------------------------------------
// fp32 -> bf16 cast, 4 elements/thread
// ---------------------------------------------------------------------------
__global__ __launch_bounds__(256) void castk(
    const float* __restrict__ in, ushort* __restrict__ out, int n4)
{
    const int i = blockIdx.x * 256 + threadIdx.x;
    if (i < n4) {
        const float4 v = ((const float4*)in)[i];
        ushort4 o;
        o.x = f2b(v.x); o.y = f2b(v.y); o.z = f2b(v.z); o.w = f2b(v.w);
        ((ushort4*)out)[i] = o;
    }
}

// ---------------------------------------------------------------------------
// Embedding: x[b,s,:] = concat(tok_emb, 3x prop embeds, pos_emb) + POS_ENC
// Writes fp32 X and bf16 X16. grid = NTOK blocks, 128 threads
// ---------------------------------------------------------------------------
__global__ __launch_bounds__(128) void embed_kernel(
    const int* __restrict__ src,
    const float* __restrict__ tok_emb,
    const float* __restrict__ pos_emb,
    const float* __restrict__ prop_W,
    const float* __restrict__ prop_b,
    float* __restrict__ X, ushort* __restrict__ X16)
{
    const int t   = blockIdx.x;       // token index in [0, NTOK)
    const int s   = t % Sc;
    const int tid = threadIdx.x;      // 0..127
    const int tok = src[t];
    float*  xr  = X   + (size_t)t * Dc;
    ushort* xr16 = X16 + (size_t)t * Dc;
    const float NLOG = -9.210340371976184f / 640.f;   // -ln(10000)/D
    const float pos  = (float)s;
    #pragma unroll
    for (int seg = 0; seg < 5; ++seg) {
        const int d = seg * 128 + tid;
        const float div = expf((float)(d & ~1) * NLOG);
        const float ang = pos * div;
        const float pe  = (d & 1) ? cosf(ang) : sinf(ang);
        float v;
        if      (seg == 0) v = tok_emb[tok * 128 + tid];
        else if (seg == 1) v = c_hydro[tok]  * prop_W[tid]       + prop_b[tid];
        else if (seg == 2) v = c_charge[tok] * prop_W[128 + tid] + prop_b[128 + tid];
        else if (seg == 3) v = c_vol[tok]    * prop_W[256 + tid] + prop_b[256 + tid];
        else               v = pos_emb[s * 128 + tid];
        const float r = v + pe;
        xr[d] = r;
        xr16[d] = f2b(r);
    }
}

// ---------------------------------------------------------------------------
// bf16 MFMA GEMM: C[M,N] = A[M,K] @ W[N,K]^T + bias[N]
// A, W bf16 row-major K-contiguous. 128x128 tile, BK=32, 256 threads (4 waves,
// each computes 64x64 via 4x4 fragments of 16x16x32). fp32 accumulate.
// Optional fp32 output Cf, optional bf16 output Cb, optional relu.
// Requires M%128==0, N%128==0, K%32==0.
// ---------------------------------------------------------------------------
__global__ __launch_bounds__(256) void gemm_bf16(
    const ushort* __restrict__ A, const ushort* __restrict__ W,
    const float* __restrict__ bias,
    float* __restrict__ Cf, ushort* __restrict__ Cb,
    int M, int N, int K, int relu)
{
    __shared__ ushort lA[128 * 32];
    __shared__ ushort lB[128 * 32];
    const int tid = threadIdx.x;
    const int wv = tid >> 6, ln = tid & 63;
    const int m0 = blockIdx.x * 128, n0 = blockIdx.y * 128;
    const int wrow = wv >> 1, wcol = wv & 1;

    // staging: chunk c = wv*64 + ln (+256); row = c>>2; colchunk = c&3
    const int c0 = wv * 64 + ln;
    const int c1 = c0 + 256;
    const ushort* gA0 = A + (size_t)(m0 + (c0 >> 2)) * K + (c0 & 3) * 8;
    const ushort* gA1 = A + (size_t)(m0 + (c1 >> 2)) * K + (c1 & 3) * 8;
    const ushort* gB0 = W + (size_t)(n0 + (c0 >> 2)) * K + (c0 & 3) * 8;
    const ushort* gB1 = W + (size_t)(n0 + (c1 >> 2)) * K + (c1 & 3) * 8;
    ushort* lA0 = lA + (wv * 64) * 8;
    ushort* lA1 = lA + (256 + wv * 64) * 8;
    ushort* lB0 = lB + (wv * 64) * 8;
    ushort* lB1 = lB + (256 + wv * 64) * 8;

    f32x4 acc[4][4];
    #pragma unroll
    for (int mi = 0; mi < 4; ++mi)
        #pragma unroll
        for (int ni = 0; ni < 4; ++ni)
            acc[mi][ni] = (f32x4){0.f, 0.f, 0.f, 0.f};

    float bval[4];
    #pragma unroll
    for (int ni = 0; ni < 4; ++ni)
        bval[ni] = bias[n0 + wcol * 64 + ni * 16 + (ln & 15)];

    const int foff = (ln & 15) * 32 + (ln >> 4) * 8;  // fragment base (ushorts)

    for (int k0 = 0; k0 < K; k0 += 32) {
        GLL16(gA0 + k0, lA0);
        GLL16(gA1 + k0, lA1);
        GLL16(gB0 + k0, lB0);
        GLL16(gB1 + k0, lB1);
        __syncthreads();            // drains vmcnt -> LDS tiles ready
        short8 af[4], bfr[4];
        #pragma unroll
        for (int mi = 0; mi < 4; ++mi)
            af[mi] = *(const short8*)&lA[(wrow * 64 + mi * 16) * 32 + foff];
        #pragma unroll
        for (int ni = 0; ni < 4; ++ni)
            bfr[ni] = *(const short8*)&lB[(wcol * 64 + ni * 16) * 32 + foff];
        #pragma unroll
        for (int mi = 0; mi < 4; ++mi)
            #pragma unroll
            for (int ni = 0; ni < 4; ++ni)
                acc[mi][ni] = __builtin_amdgcn_mfma_f32_16x16x32_bf16(
                    af[mi], bfr[ni], acc[mi][ni], 0, 0, 0);
        __syncthreads();            // LDS reads done before next stage
    }

    #pragma unroll
    for (int mi = 0; mi < 4; ++mi) {
        #pragma unroll
        for (int r = 0; r < 4; ++r) {
            const int m = m0 + wrow * 64 + mi * 16 + (ln >> 4) * 4 + r;
            #pragma unroll
            for (int ni = 0; ni < 4; ++ni) {
                const int n = n0 + wcol * 64 + ni * 16 + (ln & 15);
                float v = acc[mi][ni][r] + bval[ni];
                if (relu) v = fmaxf(v, 0.f);
                if (Cf) Cf[(size_t)m * N + n] = v;
                if (Cb) Cb[(size_t)m * N + n] = f2b(v);
            }
        }
    }
}

// ---------------------------------------------------------------------------
// MFMA flash attention (bf16 in/out, fp32 softmax/accum).
// qkv rows: [q(640) k(640) v(640)], head h = cols h*80..h*80+79 of each chunk.
// Block: 64 q-rows, 4 waves (wave = 16 q-rows). Key tiles of 64.
// QK^T: A=Q[16x96 zero-pad], B from K_lds[64][104] (pad zeroed).
// PV:  A=P via P_lds roundtrip, B from VT_lds[80][72] (V transposed).
// Fragment maps (m89/m97-verified): A/B row=lane&15, k=(lane>>4)*8+j;
// C/D col=lane&15, row=(lane>>4)*4+reg.
// LDS strides 104/72/72 ushorts -> <=2-way bank aliasing (free, m136).
// ---------------------------------------------------------------------------
__global__ __launch_bounds__(256) void flash_attn_mfma(
    const ushort* __restrict__ qkv, ushort* __restrict__ O16)
{
    const int bh = blockIdx.y;
    const int b = bh >> 3, h = bh & 7;
    const int q0 = blockIdx.x * 64;
    const int tid = threadIdx.x;
    const int wq = tid >> 6, ln = tid & 63;
    const int lg = ln >> 4;          // 0..3
    const int lc = ln & 15;          // 0..15
    const float scale = 0.1118033988749895f;   // 1/sqrt(80)

    __shared__ ushort K_lds[64][104];      // [key][dim 0..95 zero-padded]
    __shared__ ushort VT_lds[80][72];      // [dim][key]
    __shared__ ushort P_lds[4][16][72];    // per-wave [qrow][key]

    const size_t RS = 1920;
    const ushort* rowbase = qkv + (size_t)b * Sc * RS;

    // Q fragments: row = q0 + wq*16 + lc, k = kk*32 + lg*8 + j.
    // kk=2 cols 80..95 read next-chunk garbage; K_lds rows 80..95 are zero.
    short8 qf[3];
    {
        int qrow = q0 + wq * 16 + lc; if (qrow > Sc - 1) qrow = Sc - 1;
        const ushort* qp = rowbase + (size_t)qrow * RS + h * HDc + lg * 8;
        qf[0] = *(const short8*)(qp);
        qf[1] = *(const short8*)(qp + 32);
        qf[2] = *(const short8*)(qp + 64);
    }

    float m_r[4], l_r[4];
    f32x4 o_acc[5];
    #pragma unroll
    for (int r = 0; r < 4; ++r) { m_r[r] = -1e30f; l_r[r] = 0.f; }
    #pragma unroll
    for (int dt = 0; dt < 5; ++dt) o_acc[dt] = (f32x4){0.f, 0.f, 0.f, 0.f};

    for (int kt = 0; kt < 16; ++kt) {
        const int kb = kt * 64;
        __syncthreads();                       // prior tile's LDS reads done
        {   // stage K (row-major, zero-pad dims 80..95) and V^T
            const int r = tid >> 2, q4 = tid & 3;
            int krow = kb + r; if (krow > Sc - 1) krow = Sc - 1;
            const ushort* kp = rowbase + (size_t)krow * RS + Dc     + h * HDc + q4 * 20;
            const ushort* vp = rowbase + (size_t)krow * RS + 2 * Dc + h * HDc + q4 * 20;
            #pragma unroll
            for (int i = 0; i < 5; ++i) {
                const int d0 = q4 * 20 + i * 4;
                *(ushort4*)&K_lds[r][d0] = *(const ushort4*)(kp + i * 4);
                const ushort4 vv = *(const ushort4*)(vp + i * 4);
                VT_lds[d0 + 0][r] = vv.x; VT_lds[d0 + 1][r] = vv.y;
                VT_lds[d0 + 2][r] = vv.z; VT_lds[d0 + 3][r] = vv.w;
            }
            ushort4 z; z.x = 0; z.y = 0; z.z = 0; z.w = 0;
            *(ushort4*)&K_lds[r][80 + q4 * 4] = z;
        }
        __syncthreads();

        // ---- S = scale * Q K^T  (16 x 64 per wave) ----
        f32x4 s_acc[4];
        #pragma unroll
        for (int nt = 0; nt < 4; ++nt) s_acc[nt] = (f32x4){0.f, 0.f, 0.f, 0.f};
        #pragma unroll
        for (int kk = 0; kk < 3; ++kk) {
            #pragma unroll
            for (int nt = 0; nt < 4; ++nt) {
                const short8 kf = *(const short8*)&K_lds[nt * 16 + lc][kk * 32 + lg * 8];
                s_acc[nt] = __builtin_amdgcn_mfma_f32_16x16x32_bf16(
                    qf[kk], kf, s_acc[nt], 0, 0, 0);
            }
        }

        // ---- online softmax (row = lg*4 + r, key = kb + nt*16 + lc) ----
        float p[4][4];   // [nt][r]
        #pragma unroll
        for (int r = 0; r < 4; ++r) {
            float mx = -1e30f;
            #pragma unroll
            for (int nt = 0; nt < 4; ++nt) {
                float s = s_acc[nt][r] * scale;
                if (kb + nt * 16 + lc >= Sc) s = -1e30f;
                p[nt][r] = s;
                mx = fmaxf(mx, s);
            }
            #pragma unroll
            for (int mk = 1; mk < 16; mk <<= 1)
                mx = fmaxf(mx, __shfl_xor(mx, mk));
            const float m_new = fmaxf(m_r[r], mx);
            const float alpha = __expf(m_r[r] - m_new);
            float ps = 0.f;
            #pragma unroll
            for (int nt = 0; nt < 4; ++nt) {
                const float e = __expf(p[nt][r] - m_new);
                p[nt][r] = e;
                ps += e;
            }
            #pragma unroll
            for (int mk = 1; mk < 16; mk <<= 1) ps += __shfl_xor(ps, mk);
            l_r[r] = l_r[r] * alpha + ps;
            m_r[r] = m_new;
            #pragma unroll
            for (int dt = 0; dt < 5; ++dt) o_acc[dt][r] *= alpha;
        }

        // ---- P (C-layout) -> P_lds (A-layout source) ----
        #pragma unroll
        for (int nt = 0; nt < 4; ++nt)
            #pragma unroll
            for (int r = 0; r < 4; ++r)
                P_lds[wq][lg * 4 + r][nt * 16 + lc] = f2b(p[nt][r]);
        __syncthreads();                       // P visible

        // ---- O += P V  (16 x 80 per wave) ----
        #pragma unroll
        for (int kk2 = 0; kk2 < 2; ++kk2) {
            const short8 pa = *(const short8*)&P_lds[wq][lc][kk2 * 32 + lg * 8];
            #pragma unroll
            for (int dt = 0; dt < 5; ++dt) {
                const short8 vf = *(const short8*)&VT_lds[dt * 16 + lc][kk2 * 32 + lg * 8];
                o_acc[dt] = __builtin_amdgcn_mfma_f32_16x16x32_bf16(
                    pa, vf, o_acc[dt], 0, 0, 0);
            }
        }
    }

    // ---- normalize + store ----
    #pragma unroll
    for (int r = 0; r < 4; ++r) {
        const int row = q0 + wq * 16 + lg * 4 + r;
        if (row < Sc) {
            const float inv = 1.f / l_r[r];
            ushort* op = O16 + (size_t)(b * Sc + row) * Dc + h * HDc;
            #pragma unroll
            for (int dt = 0; dt < 5; ++dt)
                op[dt * 16 + lc] = f2b(o_acc[dt][r] * inv);
        }
    }
}

// ---------------------------------------------------------------------------
// x = LN(x + y) * g + b  (fp32, row=640), bf16 shadow write.
// float4 path: threads 0..159 active for memory, all 256 reduce.
// ---------------------------------------------------------------------------
__global__ __launch_bounds__(256) void add_ln(
    float* __restrict__ x, const float* __restrict__ y,
    const float* __restrict__ gamma, const float* __restrict__ beta,
    ushort* __restrict__ x16)
{
    const int row = blockIdx.x;
    float4* xr = (float4*)(x + (size_t)row * Dc);            // 160 float4
    const float4* yr = (const float4*)(y + (size_t)row * Dc);
    const int tid = threadIdx.x;
    float4 v = make_float4(0.f, 0.f, 0.f, 0.f);
    if (tid < 160) {
        const float4 a = xr[tid];
        const float4 b = yr[tid];
        v.x = a.x + b.x; v.y = a.y + b.y; v.z = a.z + b.z; v.w = a.w + b.w;
    }
    float s  = v.x + v.y + v.z + v.w;
    float ss = v.x * v.x + v.y * v.y + v.z * v.z + v.w * v.w;
    #pragma unroll
    for (int mm = 1; mm < 64; mm <<= 1) {
        s  += __shfl_xor(s, mm);
        ss += __shfl_xor(ss, mm);
    }
    __shared__ float sb[4], ssb[4];
    const int w = tid >> 6;
    if ((tid & 63) == 0) { sb[w] = s; ssb[w] = ss; }
    __syncthreads();
    s  = sb[0] + sb[1] + sb[2] + sb[3];
    ss = ssb[0] + ssb[1] + ssb[2] + ssb[3];
    const float mean = s * (1.f / 640.f);
    const float var  = ss * (1.f / 640.f) - mean * mean;
    const float inv  = rsqrtf(var + 1e-5f);
    if (tid < 160) {
        const float4 g  = ((const float4*)gamma)[tid];
        const float4 be = ((const float4*)beta)[tid];
        float4 r;
        r.x = (v.x - mean) * inv * g.x + be.x;
        r.y = (v.y - mean) * inv * g.y + be.y;
        r.z = (v.z - mean) * inv * g.z + be.z;
        r.w = (v.w - mean) * inv * g.w + be.w;
        xr[tid] = r;
        ushort4 o;
        o.x = f2b(r.x); o.y = f2b(r.y); o.z = f2b(r.z); o.w = f2b(r.w);
        ((ushort4*)(x16 + (size_t)row * Dc))[tid] = o;
    }
}

// ---------------------------------------------------------------------------
// seq_rep = mean over S, two stages
// ---------------------------------------------------------------------------
__global__ __launch_bounds__(256) void seq_partial(
    const float* __restrict__ X, float* __restrict__ part)
{
    const int b = blockIdx.x, c = blockIdx.y;   // c in [0,10)
    const float* base = X + ((size_t)b * Sc + c * 100) * Dc;
    const int tid = threadIdx.x;
    float a0 = 0.f, a1 = 0.f, a2 = 0.f;
    for (int s = 0; s < 100; ++s) {
        const float* row = base + (size_t)s * Dc;
        a0 += row[tid];
        a1 += row[tid + 256];
        if (tid < 128) a2 += row[tid + 512];
    }
    float* p = part + (size_t)(b * 10 + c) * Dc;
    p[tid] = a0; p[tid + 256] = a1;
    if (tid < 128) p[tid + 512] = a2;
}

__global__ __launch_bounds__(256) void seq_final(
    const float* __restrict__ part, float* __restrict__ seq)
{
    const int b = blockIdx.x, tid = threadIdx.x;
    for (int d = tid; d < Dc; d += 256) {
        float s = 0.f;
        for (int c = 0; c < 10; ++c) s += part[(size_t)(b * 10 + c) * Dc + d];
        seq[b * Dc + d] = s * (1.f / 1000.f);
    }
}

// ---------------------------------------------------------------------------
// Head MLP (tiny, fp32): one block per batch element.
// ---------------------------------------------------------------------------
__global__ __launch_bounds__(256) void head_mlp(
    const float* __restrict__ seq,
    const float* __restrict__ fW1, const float* __restrict__ fb1,
    const float* __restrict__ fW2, const float* __restrict__ fb2,
    const float* __restrict__ rW1, const float* __restrict__ rb1,
    const float* __restrict__ rW2, const float* __restrict__ rb2,
    float* __restrict__ out)
{
    __shared__ float sq[640];
    __shared__ float h1[640];
    __shared__ float h2[320];
    __shared__ float h3[160];
    __shared__ float red[256];
    const int b = blockIdx.x, tid = threadIdx.x;
    for (int i = tid; i < 640; i += 256) sq[i] = seq[b * 640 + i];
    __syncthreads();
    for (int e = tid; e < 640; e += 256) {
        const float* w = fW1 + (size_t)e * 1312;
        float acc = fb1[e];
        for (int k = 0; k < 640; ++k) acc = fmaf(sq[k], w[k] + w[672 + k], acc);
        h1[e] = fmaxf(acc, 0.f);
    }
    __syncthreads();
    for (int e = tid; e < 320; e += 256) {
        const float* w = fW2 + (size_t)e * 640;
        float acc = fb2[e];
        for (int k = 0; k < 640; ++k) acc = fmaf(h1[k], w[k], acc);
        h2[e] = acc;
    }
    __syncthreads();
    for (int e = tid; e < 160; e += 256) {
        const float* w = rW1 + (size_t)e * 320;
        float acc = rb1[e];
        for (int k = 0; k < 320; ++k) acc = fmaf(h2[k], w[k], acc);
        h3[e] = fmaxf(acc, 0.f);
    }
    __syncthreads();
    red[tid] = (tid < 160) ? h3[tid] * rW2[tid] : 0.f;
    __syncthreads();
    for (int off = 128; off > 0; off >>= 1) {
        if (tid < off) red[tid] += red[tid + off];
        __syncthreads();
    }
    if (tid == 0) out[b] = red[0] + rb2[0];
}

// ---------------------------------------------------------------------------
extern "C" void kernel_launch(void* const* d_in, const int* in_sizes, int n_in,
                              void* d_out, int out_size, void* d_ws, size_t ws_size,
                              hipStream_t stream)
{
    const int*   src     = (const int*)  d_in[0];
    const float* tok_emb = (const float*)d_in[1];
    const float* pos_emb = (const float*)d_in[2];
    const float* prop_W  = (const float*)d_in[3];
    const float* prop_b  = (const float*)d_in[4];
    const float* Wqkv    = (const float*)d_in[5];
    const float* bqkv    = (const float*)d_in[6];
    const float* Wo      = (const float*)d_in[7];
    const float* bo      = (const float*)d_in[8];
    const float* W1      = (const float*)d_in[9];
    const float* b1      = (const float*)d_in[10];
    const float* W2      = (const float*)d_in[11];
    const float* b2      = (const float*)d_in[12];
    const float* ln1_g   = (const float*)d_in[13];
    const float* ln1_b   = (const float*)d_in[14];
    const float* ln2_g   = (const float*)d_in[15];
    const float* ln2_b   = (const float*)d_in[16];
    const float* fW1     = (const float*)d_in[17];
    const float* fb1     = (const float*)d_in[18];
    const float* fW2     = (const float*)d_in[19];
    const float* fb2     = (const float*)d_in[20];
    const float* rW1     = (const float*)d_in[21];
    const float* rb1     = (const float*)d_in[22];
    const float* rW2     = (const float*)d_in[23];
    const float* rb2     = (const float*)d_in[24];
    float* out = (float*)d_out;

    // workspace layout (f32 units), total ~240 MiB
    float* ws    = (float*)d_ws;
    float*  X     = ws;                        // 10,240,000
    ushort* X16   = (ushort*)(X + 10240000);   //  5,120,000 f32 slots
    float*  R1    = X + 10240000 + 5120000;    // 16,384,000 (QKV16 / FF16 arena)
    ushort* R1u   = (ushort*)R1;
    ushort* OB16  = (ushort*)(R1 + 16384000);  //  5,120,000 f32 slots
    float*  OPROJ = R1 + 16384000 + 5120000;   // 10,240,000
    ushort* W16   = (ushort*)(OPROJ + 10240000); // 12,779,520 f32 slots
    float*  PART  = OPROJ + 10240000 + 12779520; // 102,400
    float*  SEQ   = PART + 102400;               // 10,240

    // bf16 weight arenas (ushort offsets inside W16)
    ushort* Wqkv16 = W16;                 // 6*1920*640 = 7,372,800
    ushort* Wo16   = W16 + 7372800;       // 6*640*640  = 2,457,600
    ushort* W116   = W16 + 9830400;       // 6*2048*640 = 7,864,320
    ushort* W216   = W16 + 17694720;      // 6*640*2048 = 7,864,320

    // convert weights to bf16 (once per launch)
    castk<<<7200, 256, 0, stream>>>(Wqkv, Wqkv16, 1843200);
    castk<<<2400, 256, 0, stream>>>(Wo,   Wo16,    614400);
    castk<<<7680, 256, 0, stream>>>(W1,   W116,   1966080);
    castk<<<7680, 256, 0, stream>>>(W2,   W216,   1966080);

    embed_kernel<<<NTOK, 128, 0, stream>>>(src, tok_emb, pos_emb, prop_W, prop_b, X, X16);

    for (int l = 0; l < Lc; ++l) {
        // qkv (bf16 out) : [16000 x 1920]
        gemm_bf16<<<dim3(125, 15), 256, 0, stream>>>(
            X16, Wqkv16 + (size_t)l * 1228800, bqkv + (size_t)l * 1920,
            nullptr, R1u, NTOK, 1920, 640, 0);
        // attention -> OB16 (bf16)
        flash_attn_mfma<<<dim3(16, 128), 256, 0, stream>>>(R1u, OB16);
        // o-proj -> OPROJ (f32)
        gemm_bf16<<<dim3(125, 5), 256, 0, stream>>>(
            OB16, Wo16 + (size_t)l * 409600, bo + (size_t)l * 640,
            OPROJ, nullptr, NTOK, 640, 640, 0);
        // x = LN(x + o); emit bf16 shadow
        add_ln<<<NTOK, 256, 0, stream>>>(X, OPROJ, ln1_g + l * 640, ln1_b + l * 640, X16);
        // ff1 = relu(x @ W1^T + b1) -> bf16 only [16000 x 2048]
        gemm_bf16<<<dim3(125, 16), 256, 0, stream>>>(
            X16, W116 + (size_t)l * 1310720, b1 + (size_t)l * 2048,
            nullptr, R1u, NTOK, 2048, 640, 1);
        // ff2 -> OPROJ (f32)
        gemm_bf16<<<dim3(125, 5), 256, 0, stream>>>(
            R1u, W216 + (size_t)l * 1310720, b2 + (size_t)l * 640,
            OPROJ, nullptr, NTOK, 640, 2048, 0);
        // x = LN(x + ff); emit bf16 shadow
        add_ln<<<NTOK, 256, 0, stream>>>(X, OPROJ, ln2_g + l * 640, ln2_b + l * 640, X16);
    }

    seq_partial<<<dim3(16, 10), 256, 0, stream>>>(X, PART);
    seq_final<<<16, 256, 0, stream>>>(PART, SEQ);
    head_mlp<<<16, 256, 0, stream>>>(SEQ, fW1, fb1, fW2, fb2, rW1, rb1, rW2, rb2, out);
}

// Round 6
// 2806.944 us; speedup vs baseline: 1.1061x; 1.1061x over previous
//
#include <hip/hip_runtime.h>
#include <math.h>

// Problem constants
#define Bc   16
#define Sc   1000
#define Dc   640
#define EMBc 128
#define Hc   8
#define HDc  80
#define Lc   6
#define DFFc 2048
#define NTOK (Bc * Sc)          // 16000

typedef __attribute__((ext_vector_type(8))) short short8;
typedef __attribute__((ext_vector_type(4))) float f32x4;

__device__ __forceinline__ float b2f(ushort u) {
    return __uint_as_float(((unsigned)u) << 16);
}
__device__ __forceinline__ ushort f2b(float f) {
    unsigned u = __float_as_uint(f);
    unsigned r = (u + 0x7fffu + ((u >> 16) & 1u)) >> 16;
    return (ushort)r;
}

#define GLL16(gp, lp) __builtin_amdgcn_global_load_lds( \
    (const __attribute__((address_space(1))) void*)(gp), \
    (__attribute__((address_space(3))) void*)(lp), 16, 0, 0)

// Property tables (PROP_TABLES constant in reference)
__constant__ float c_hydro[22]  = {1.8f,-4.5f,-3.5f,-3.5f,2.5f,-3.5f,-3.5f,-0.4f,-3.2f,4.5f,3.8f,-3.9f,1.9f,2.8f,-1.6f,-0.8f,-0.7f,-0.9f,-1.3f,4.2f,0.f,0.f};
__constant__ float c_charge[22] = {0.f,1.f,0.f,-1.f,0.f,0.f,-1.f,0.f,1.f,0.f,0.f,1.f,0.f,0.f,0.f,0.f,0.f,0.f,0.f,0.f,0.f,0.f};
__constant__ float c_vol[22]    = {88.6f,173.4f,114.1f,111.1f,108.5f,143.9f,138.4f,60.1f,153.2f,166.7f,166.7f,168.6f,162.9f,189.9f,112.7f,89.0f,116.1f,227.8f,193.6f,140.0f,0.f,100.f};

// ---------------------------------------------------------------------------
// fp32 -> bf16 cast, 4 elements/thread
// ---------------------------------------------------------------------------
__global__ __launch_bounds__(256) void castk(
    const float* __restrict__ in, ushort* __restrict__ out, int n4)
{
    const int i = blockIdx.x * 256 + threadIdx.x;
    if (i < n4) {
        const float4 v = ((const float4*)in)[i];
        ushort4 o;
        o.x = f2b(v.x); o.y = f2b(v.y); o.z = f2b(v.z); o.w = f2b(v.w);
        ((ushort4*)out)[i] = o;
    }
}

// ---------------------------------------------------------------------------
// Embedding: x[b,s,:] = concat(tok_emb, 3x prop embeds, pos_emb) + POS_ENC
// ---------------------------------------------------------------------------
__global__ __launch_bounds__(128) void embed_kernel(
    const int* __restrict__ src,
    const float* __restrict__ tok_emb,
    const float* __restrict__ pos_emb,
    const float* __restrict__ prop_W,
    const float* __restrict__ prop_b,
    float* __restrict__ X, ushort* __restrict__ X16)
{
    const int t   = blockIdx.x;
    const int s   = t % Sc;
    const int tid = threadIdx.x;
    const int tok = src[t];
    float*  xr  = X   + (size_t)t * Dc;
    ushort* xr16 = X16 + (size_t)t * Dc;
    const float NLOG = -9.210340371976184f / 640.f;
    const float pos  = (float)s;
    #pragma unroll
    for (int seg = 0; seg < 5; ++seg) {
        const int d = seg * 128 + tid;
        const float div = expf((float)(d & ~1) * NLOG);
        const float ang = pos * div;
        const float pe  = (d & 1) ? cosf(ang) : sinf(ang);
        float v;
        if      (seg == 0) v = tok_emb[tok * 128 + tid];
        else if (seg == 1) v = c_hydro[tok]  * prop_W[tid]       + prop_b[tid];
        else if (seg == 2) v = c_charge[tok] * prop_W[128 + tid] + prop_b[128 + tid];
        else if (seg == 3) v = c_vol[tok]    * prop_W[256 + tid] + prop_b[256 + tid];
        else               v = pos_emb[s * 128 + tid];
        const float r = v + pe;
        xr[d] = r;
        xr16[d] = f2b(r);
    }
}

// ---------------------------------------------------------------------------
// bf16 MFMA GEMM: C = A @ W^T + bias. 128x128 tile, BK=64 (two 32-halves per
// barrier pair -> 8 GLL16 + 32 MFMA between syncs). M%128==0, N%128==0, K%64==0.
// ---------------------------------------------------------------------------
__global__ __launch_bounds__(256) void gemm_bf16(
    const ushort* __restrict__ A, const ushort* __restrict__ W,
    const float* __restrict__ bias,
    float* __restrict__ Cf, ushort* __restrict__ Cb,
    int M, int N, int K, int relu)
{
    __shared__ ushort lA[2][4096];    // [half][128 rows x 32 cols]
    __shared__ ushort lB[2][4096];
    const int tid = threadIdx.x;
    const int wv = tid >> 6, ln = tid & 63;
    const int m0 = blockIdx.x * 128, n0 = blockIdx.y * 128;
    const int wrow = wv >> 1, wcol = wv & 1;
    const int lg = ln >> 4, lc = ln & 15;

    const int c0 = wv * 64 + ln;       // chunks: rows 0..63
    const int c1 = c0 + 256;           // rows 64..127
    const ushort* gA0 = A + (size_t)(m0 + (c0 >> 2)) * K + (c0 & 3) * 8;
    const ushort* gA1 = A + (size_t)(m0 + (c1 >> 2)) * K + (c1 & 3) * 8;
    const ushort* gB0 = W + (size_t)(n0 + (c0 >> 2)) * K + (c0 & 3) * 8;
    const ushort* gB1 = W + (size_t)(n0 + (c1 >> 2)) * K + (c1 & 3) * 8;

    f32x4 acc[4][4];
    #pragma unroll
    for (int mi = 0; mi < 4; ++mi)
        #pragma unroll
        for (int ni = 0; ni < 4; ++ni)
            acc[mi][ni] = (f32x4){0.f, 0.f, 0.f, 0.f};

    float bval[4];
    #pragma unroll
    for (int ni = 0; ni < 4; ++ni)
        bval[ni] = bias[n0 + wcol * 64 + ni * 16 + lc];

    const int foff = lc * 32 + lg * 8;     // fragment base within a half

    for (int k0 = 0; k0 < K; k0 += 64) {
        GLL16(gA0 + k0,      &lA[0][wv * 512]);
        GLL16(gA1 + k0,      &lA[0][2048 + wv * 512]);
        GLL16(gA0 + k0 + 32, &lA[1][wv * 512]);
        GLL16(gA1 + k0 + 32, &lA[1][2048 + wv * 512]);
        GLL16(gB0 + k0,      &lB[0][wv * 512]);
        GLL16(gB1 + k0,      &lB[0][2048 + wv * 512]);
        GLL16(gB0 + k0 + 32, &lB[1][wv * 512]);
        GLL16(gB1 + k0 + 32, &lB[1][2048 + wv * 512]);
        __syncthreads();            // drains vmcnt -> LDS tiles ready
        #pragma unroll
        for (int hh = 0; hh < 2; ++hh) {
            short8 af[4], bfr[4];
            #pragma unroll
            for (int mi = 0; mi < 4; ++mi)
                af[mi] = *(const short8*)&lA[hh][(wrow * 64 + mi * 16) * 32 + foff];
            #pragma unroll
            for (int ni = 0; ni < 4; ++ni)
                bfr[ni] = *(const short8*)&lB[hh][(wcol * 64 + ni * 16) * 32 + foff];
            #pragma unroll
            for (int mi = 0; mi < 4; ++mi)
                #pragma unroll
                for (int ni = 0; ni < 4; ++ni)
                    acc[mi][ni] = __builtin_amdgcn_mfma_f32_16x16x32_bf16(
                        af[mi], bfr[ni], acc[mi][ni], 0, 0, 0);
        }
        __syncthreads();            // LDS reads done before next stage
    }

    #pragma unroll
    for (int mi = 0; mi < 4; ++mi) {
        #pragma unroll
        for (int r = 0; r < 4; ++r) {
            const int m = m0 + wrow * 64 + mi * 16 + lg * 4 + r;
            #pragma unroll
            for (int ni = 0; ni < 4; ++ni) {
                const int n = n0 + wcol * 64 + ni * 16 + lc;
                float v = acc[mi][ni][r] + bval[ni];
                if (relu) v = fmaxf(v, 0.f);
                if (Cf) Cf[(size_t)m * N + n] = v;
                if (Cb) Cb[(size_t)m * N + n] = f2b(v);
            }
        }
    }
}

// ---------------------------------------------------------------------------
// MFMA flash attention, QBLK=128 (8 waves, 512 thr), KVBLK=64, T14 async-stage.
// Staging role-split: waves 0-3 stage K (row-major, dims 80..95 zeroed),
// waves 4-7 stage V transposed. Global->reg prefetch of tile t+1 issued
// before tile t's compute; reg->LDS write after the top barrier.
// Fragment maps (verified in hardware round 4): A/B row=lane&15,
// k=(lane>>4)*8+j; C/D col=lane&15, row=(lane>>4)*4+reg.
// P_lds is strictly per-wave: ds_write -> ds_read same wave, DS pipe
// in-order per wave, no barrier needed. (If validation ever fails, add
// __syncthreads() before the PV loop as first suspect.)
// ---------------------------------------------------------------------------
__global__ __launch_bounds__(512, 4) void flash_attn_mfma(
    const ushort* __restrict__ qkv, ushort* __restrict__ O16)
{
    const int bh = blockIdx.y;
    const int b = bh >> 3, h = bh & 7;
    const int q0 = blockIdx.x * 128;
    const int tid = threadIdx.x;
    const int wq = tid >> 6, ln = tid & 63;
    const int lg = ln >> 4, lc = ln & 15;
    const float scale = 0.1118033988749895f;   // 1/sqrt(80)

    __shared__ ushort K_lds[64][104];      // [key][dim 0..95, pad zeroed]
    __shared__ ushort VT_lds[80][72];      // [dim][key]
    __shared__ ushort P_lds[8][16][72];    // per-wave [qrow][key]

    const size_t RS = 1920;
    const ushort* rowbase = qkv + (size_t)b * Sc * RS;

    // Q fragments (dims 80..95 read neighbor data; K_lds rows 80..95 are zero)
    short8 qf[3];
    {
        int qrow = q0 + wq * 16 + lc; if (qrow > Sc - 1) qrow = Sc - 1;
        const ushort* qp = rowbase + (size_t)qrow * RS + h * HDc + lg * 8;
        qf[0] = *(const short8*)(qp);
        qf[1] = *(const short8*)(qp + 32);
        qf[2] = *(const short8*)(qp + 64);
    }

    // staging role
    const bool sideV = tid >= 256;
    const int st = tid & 255;
    const int sr = st >> 2, sq4 = st & 3;     // key-row 0..63, 20-dim chunk
    const size_t chunk_off = (sideV ? 2 * (size_t)Dc : (size_t)Dc) + h * HDc + sq4 * 20;
    ushort4 hold[5];

    {   // prologue: load tile 0 into regs
        int krow = sr; if (krow > Sc - 1) krow = Sc - 1;
        const ushort* p = rowbase + (size_t)krow * RS + chunk_off;
        #pragma unroll
        for (int i = 0; i < 5; ++i) hold[i] = *(const ushort4*)(p + i * 4);
    }

    float m_r[4], l_r[4];
    f32x4 o_acc[5];
    #pragma unroll
    for (int r = 0; r < 4; ++r) { m_r[r] = -1e30f; l_r[r] = 0.f; }
    #pragma unroll
    for (int dt = 0; dt < 5; ++dt) o_acc[dt] = (f32x4){0.f, 0.f, 0.f, 0.f};

    for (int kt = 0; kt < 16; ++kt) {
        const int kb = kt * 64;
        __syncthreads();                       // prior tile's LDS reads done
        if (!sideV) {                          // write staged K
            #pragma unroll
            for (int i = 0; i < 5; ++i)
                *(ushort4*)&K_lds[sr][sq4 * 20 + i * 4] = hold[i];
            ushort4 z; z.x = 0; z.y = 0; z.z = 0; z.w = 0;
            *(ushort4*)&K_lds[sr][80 + sq4 * 4] = z;
        } else {                               // write staged V (transposed)
            #pragma unroll
            for (int i = 0; i < 5; ++i) {
                const int d0 = sq4 * 20 + i * 4;
                VT_lds[d0 + 0][sr] = hold[i].x; VT_lds[d0 + 1][sr] = hold[i].y;
                VT_lds[d0 + 2][sr] = hold[i].z; VT_lds[d0 + 3][sr] = hold[i].w;
            }
        }
        __syncthreads();                       // staging visible

        if (kt < 15) {                         // T14: prefetch next tile -> regs
            int krow = kb + 64 + sr; if (krow > Sc - 1) krow = Sc - 1;
            const ushort* p = rowbase + (size_t)krow * RS + chunk_off;
            #pragma unroll
            for (int i = 0; i < 5; ++i) hold[i] = *(const ushort4*)(p + i * 4);
        }

        // ---- S = scale * Q K^T  (16 x 64 per wave) ----
        f32x4 s_acc[4];
        #pragma unroll
        for (int nt = 0; nt < 4; ++nt) s_acc[nt] = (f32x4){0.f, 0.f, 0.f, 0.f};
        __builtin_amdgcn_s_setprio(1);
        #pragma unroll
        for (int kk = 0; kk < 3; ++kk) {
            #pragma unroll
            for (int nt = 0; nt < 4; ++nt) {
                const short8 kf = *(const short8*)&K_lds[nt * 16 + lc][kk * 32 + lg * 8];
                s_acc[nt] = __builtin_amdgcn_mfma_f32_16x16x32_bf16(
                    qf[kk], kf, s_acc[nt], 0, 0, 0);
            }
        }
        __builtin_amdgcn_s_setprio(0);

        // ---- online softmax (row = lg*4 + r, key = kb + nt*16 + lc) ----
        #pragma unroll
        for (int r = 0; r < 4; ++r) {
            float mx = -1e30f;
            #pragma unroll
            for (int nt = 0; nt < 4; ++nt) {
                float s = s_acc[nt][r] * scale;
                if (kb + nt * 16 + lc >= Sc) s = -1e30f;
                s_acc[nt][r] = s;
                mx = fmaxf(mx, s);
            }
            #pragma unroll
            for (int mk = 1; mk < 16; mk <<= 1)
                mx = fmaxf(mx, __shfl_xor(mx, mk));
            const float m_new = fmaxf(m_r[r], mx);
            const float alpha = __expf(m_r[r] - m_new);
            float ps = 0.f;
            #pragma unroll
            for (int nt = 0; nt < 4; ++nt) {
                const float e = __expf(s_acc[nt][r] - m_new);
                s_acc[nt][r] = e;
                ps += e;
            }
            #pragma unroll
            for (int mk = 1; mk < 16; mk <<= 1) ps += __shfl_xor(ps, mk);
            l_r[r] = l_r[r] * alpha + ps;
            m_r[r] = m_new;
            #pragma unroll
            for (int dt = 0; dt < 5; ++dt) o_acc[dt][r] *= alpha;
        }

        // ---- P (C-layout) -> P_lds (wave-local; DS pipe in-order per wave) ----
        #pragma unroll
        for (int nt = 0; nt < 4; ++nt)
            #pragma unroll
            for (int r = 0; r < 4; ++r)
                P_lds[wq][lg * 4 + r][nt * 16 + lc] = f2b(s_acc[nt][r]);

        // ---- O += P V  (16 x 80 per wave) ----
        __builtin_amdgcn_s_setprio(1);
        #pragma unroll
        for (int kk2 = 0; kk2 < 2; ++kk2) {
            const short8 pa = *(const short8*)&P_lds[wq][lc][kk2 * 32 + lg * 8];
            #pragma unroll
            for (int dt = 0; dt < 5; ++dt) {
                const short8 vf = *(const short8*)&VT_lds[dt * 16 + lc][kk2 * 32 + lg * 8];
                o_acc[dt] = __builtin_amdgcn_mfma_f32_16x16x32_bf16(
                    pa, vf, o_acc[dt], 0, 0, 0);
            }
        }
        __builtin_amdgcn_s_setprio(0);
    }

    // ---- normalize + store ----
    #pragma unroll
    for (int r = 0; r < 4; ++r) {
        const int row = q0 + wq * 16 + lg * 4 + r;
        if (row < Sc) {
            const float inv = 1.f / l_r[r];
            ushort* op = O16 + (size_t)(b * Sc + row) * Dc + h * HDc;
            #pragma unroll
            for (int dt = 0; dt < 5; ++dt)
                op[dt * 16 + lc] = f2b(o_acc[dt][r] * inv);
        }
    }
}

// ---------------------------------------------------------------------------
// x = LN(x + y) * g + b  (fp32, row=640), bf16 shadow write. float4 path.
// ---------------------------------------------------------------------------
__global__ __launch_bounds__(256) void add_ln(
    float* __restrict__ x, const float* __restrict__ y,
    const float* __restrict__ gamma, const float* __restrict__ beta,
    ushort* __restrict__ x16)
{
    const int row = blockIdx.x;
    float4* xr = (float4*)(x + (size_t)row * Dc);            // 160 float4
    const float4* yr = (const float4*)(y + (size_t)row * Dc);
    const int tid = threadIdx.x;
    float4 v = make_float4(0.f, 0.f, 0.f, 0.f);
    if (tid < 160) {
        const float4 a = xr[tid];
        const float4 b = yr[tid];
        v.x = a.x + b.x; v.y = a.y + b.y; v.z = a.z + b.z; v.w = a.w + b.w;
    }
    float s  = v.x + v.y + v.z + v.w;
    float ss = v.x * v.x + v.y * v.y + v.z * v.z + v.w * v.w;
    #pragma unroll
    for (int mm = 1; mm < 64; mm <<= 1) {
        s  += __shfl_xor(s, mm);
        ss += __shfl_xor(ss, mm);
    }
    __shared__ float sb[4], ssb[4];
    const int w = tid >> 6;
    if ((tid & 63) == 0) { sb[w] = s; ssb[w] = ss; }
    __syncthreads();
    s  = sb[0] + sb[1] + sb[2] + sb[3];
    ss = ssb[0] + ssb[1] + ssb[2] + ssb[3];
    const float mean = s * (1.f / 640.f);
    const float var  = ss * (1.f / 640.f) - mean * mean;
    const float inv  = rsqrtf(var + 1e-5f);
    if (tid < 160) {
        const float4 g  = ((const float4*)gamma)[tid];
        const float4 be = ((const float4*)beta)[tid];
        float4 r;
        r.x = (v.x - mean) * inv * g.x + be.x;
        r.y = (v.y - mean) * inv * g.y + be.y;
        r.z = (v.z - mean) * inv * g.z + be.z;
        r.w = (v.w - mean) * inv * g.w + be.w;
        xr[tid] = r;
        ushort4 o;
        o.x = f2b(r.x); o.y = f2b(r.y); o.z = f2b(r.z); o.w = f2b(r.w);
        ((ushort4*)(x16 + (size_t)row * Dc))[tid] = o;
    }
}

// ---------------------------------------------------------------------------
// seq_rep = mean over S, two stages
// ---------------------------------------------------------------------------
__global__ __launch_bounds__(256) void seq_partial(
    const float* __restrict__ X, float* __restrict__ part)
{
    const int b = blockIdx.x, c = blockIdx.y;   // c in [0,10)
    const float* base = X + ((size_t)b * Sc + c * 100) * Dc;
    const int tid = threadIdx.x;
    float a0 = 0.f, a1 = 0.f, a2 = 0.f;
    for (int s = 0; s < 100; ++s) {
        const float* row = base + (size_t)s * Dc;
        a0 += row[tid];
        a1 += row[tid + 256];
        if (tid < 128) a2 += row[tid + 512];
    }
    float* p = part + (size_t)(b * 10 + c) * Dc;
    p[tid] = a0; p[tid + 256] = a1;
    if (tid < 128) p[tid + 512] = a2;
}

__global__ __launch_bounds__(256) void seq_final(
    const float* __restrict__ part, float* __restrict__ seq)
{
    const int b = blockIdx.x, tid = threadIdx.x;
    for (int d = tid; d < Dc; d += 256) {
        float s = 0.f;
        for (int c = 0; c < 10; ++c) s += part[(size_t)(b * 10 + c) * Dc + d];
        seq[b * Dc + d] = s * (1.f / 1000.f);
    }
}

// ---------------------------------------------------------------------------
// Head MLP (tiny, fp32): one block per batch element.
// ---------------------------------------------------------------------------
__global__ __launch_bounds__(256) void head_mlp(
    const float* __restrict__ seq,
    const float* __restrict__ fW1, const float* __restrict__ fb1,
    const float* __restrict__ fW2, const float* __restrict__ fb2,
    const float* __restrict__ rW1, const float* __restrict__ rb1,
    const float* __restrict__ rW2, const float* __restrict__ rb2,
    float* __restrict__ out)
{
    __shared__ float sq[640];
    __shared__ float h1[640];
    __shared__ float h2[320];
    __shared__ float h3[160];
    __shared__ float red[256];
    const int b = blockIdx.x, tid = threadIdx.x;
    for (int i = tid; i < 640; i += 256) sq[i] = seq[b * 640 + i];
    __syncthreads();
    for (int e = tid; e < 640; e += 256) {
        const float* w = fW1 + (size_t)e * 1312;
        float acc = fb1[e];
        for (int k = 0; k < 640; ++k) acc = fmaf(sq[k], w[k] + w[672 + k], acc);
        h1[e] = fmaxf(acc, 0.f);
    }
    __syncthreads();
    for (int e = tid; e < 320; e += 256) {
        const float* w = fW2 + (size_t)e * 640;
        float acc = fb2[e];
        for (int k = 0; k < 640; ++k) acc = fmaf(h1[k], w[k], acc);
        h2[e] = acc;
    }
    __syncthreads();
    for (int e = tid; e < 160; e += 256) {
        const float* w = rW1 + (size_t)e * 320;
        float acc = rb1[e];
        for (int k = 0; k < 320; ++k) acc = fmaf(h2[k], w[k], acc);
        h3[e] = fmaxf(acc, 0.f);
    }
    __syncthreads();
    red[tid] = (tid < 160) ? h3[tid] * rW2[tid] : 0.f;
    __syncthreads();
    for (int off = 128; off > 0; off >>= 1) {
        if (tid < off) red[tid] += red[tid + off];
        __syncthreads();
    }
    if (tid == 0) out[b] = red[0] + rb2[0];
}

// ---------------------------------------------------------------------------
extern "C" void kernel_launch(void* const* d_in, const int* in_sizes, int n_in,
                              void* d_out, int out_size, void* d_ws, size_t ws_size,
                              hipStream_t stream)
{
    const int*   src     = (const int*)  d_in[0];
    const float* tok_emb = (const float*)d_in[1];
    const float* pos_emb = (const float*)d_in[2];
    const float* prop_W  = (const float*)d_in[3];
    const float* prop_b  = (const float*)d_in[4];
    const float* Wqkv    = (const float*)d_in[5];
    const float* bqkv    = (const float*)d_in[6];
    const float* Wo      = (const float*)d_in[7];
    const float* bo      = (const float*)d_in[8];
    const float* W1      = (const float*)d_in[9];
    const float* b1      = (const float*)d_in[10];
    const float* W2      = (const float*)d_in[11];
    const float* b2      = (const float*)d_in[12];
    const float* ln1_g   = (const float*)d_in[13];
    const float* ln1_b   = (const float*)d_in[14];
    const float* ln2_g   = (const float*)d_in[15];
    const float* ln2_b   = (const float*)d_in[16];
    const float* fW1     = (const float*)d_in[17];
    const float* fb1     = (const float*)d_in[18];
    const float* fW2     = (const float*)d_in[19];
    const float* fb2     = (const float*)d_in[20];
    const float* rW1     = (const float*)d_in[21];
    const float* rb1     = (const float*)d_in[22];
    const float* rW2     = (const float*)d_in[23];
    const float* rb2     = (const float*)d_in[24];
    float* out = (float*)d_out;

    // workspace layout (f32 units), total ~240 MiB
    float* ws    = (float*)d_ws;
    float*  X     = ws;                        // 10,240,000
    ushort* X16   = (ushort*)(X + 10240000);   //  5,120,000 f32 slots
    float*  R1    = X + 10240000 + 5120000;    // 16,384,000 (QKV16 / FF16 arena)
    ushort* R1u   = (ushort*)R1;
    ushort* OB16  = (ushort*)(R1 + 16384000);  //  5,120,000 f32 slots
    float*  OPROJ = R1 + 16384000 + 5120000;   // 10,240,000
    ushort* W16   = (ushort*)(OPROJ + 10240000); // 12,779,520 f32 slots
    float*  PART  = OPROJ + 10240000 + 12779520; // 102,400
    float*  SEQ   = PART + 102400;               // 10,240

    // bf16 weight arenas (ushort offsets inside W16)
    ushort* Wqkv16 = W16;                 // 6*1920*640 = 7,372,800
    ushort* Wo16   = W16 + 7372800;       // 6*640*640  = 2,457,600
    ushort* W116   = W16 + 9830400;       // 6*2048*640 = 7,864,320
    ushort* W216   = W16 + 17694720;      // 6*640*2048 = 7,864,320

    // convert weights to bf16 (once per launch)
    castk<<<7200, 256, 0, stream>>>(Wqkv, Wqkv16, 1843200);
    castk<<<2400, 256, 0, stream>>>(Wo,   Wo16,    614400);
    castk<<<7680, 256, 0, stream>>>(W1,   W116,   1966080);
    castk<<<7680, 256, 0, stream>>>(W2,   W216,   1966080);

    embed_kernel<<<NTOK, 128, 0, stream>>>(src, tok_emb, pos_emb, prop_W, prop_b, X, X16);

    for (int l = 0; l < Lc; ++l) {
        // qkv (bf16 out) : [16000 x 1920]
        gemm_bf16<<<dim3(125, 15), 256, 0, stream>>>(
            X16, Wqkv16 + (size_t)l * 1228800, bqkv + (size_t)l * 1920,
            nullptr, R1u, NTOK, 1920, 640, 0);
        // attention -> OB16 (bf16)
        flash_attn_mfma<<<dim3(8, 128), 512, 0, stream>>>(R1u, OB16);
        // o-proj -> OPROJ (f32)
        gemm_bf16<<<dim3(125, 5), 256, 0, stream>>>(
            OB16, Wo16 + (size_t)l * 409600, bo + (size_t)l * 640,
            OPROJ, nullptr, NTOK, 640, 640, 0);
        // x = LN(x + o); emit bf16 shadow
        add_ln<<<NTOK, 256, 0, stream>>>(X, OPROJ, ln1_g + l * 640, ln1_b + l * 640, X16);
        // ff1 = relu(x @ W1^T + b1) -> bf16 only [16000 x 2048]
        gemm_bf16<<<dim3(125, 16), 256, 0, stream>>>(
            X16, W116 + (size_t)l * 1310720, b1 + (size_t)l * 2048,
            nullptr, R1u, NTOK, 2048, 640, 1);
        // ff2 -> OPROJ (f32)
        gemm_bf16<<<dim3(125, 5), 256, 0, stream>>>(
            R1u, W216 + (size_t)l * 1310720, b2 + (size_t)l * 640,
            OPROJ, nullptr, NTOK, 640, 2048, 0);
        // x = LN(x + ff); emit bf16 shadow
        add_ln<<<NTOK, 256, 0, stream>>>(X, OPROJ, ln2_g + l * 640, ln2_b + l * 640, X16);
    }

    seq_partial<<<dim3(16, 10), 256, 0, stream>>>(X, PART);
    seq_final<<<16, 256, 0, stream>>>(PART, SEQ);
    head_mlp<<<16, 256, 0, stream>>>(SEQ, fW1, fb1, fW2, fb2, rW1, rb1, rW2, rb2, out);
}

// Round 8
// 2640.444 us; speedup vs baseline: 1.1759x; 1.0631x over previous
//
#include <hip/hip_runtime.h>
#include <math.h>

// Problem constants
#define Bc   16
#define Sc   1000
#define Dc   640
#define EMBc 128
#define Hc   8
#define HDc  80
#define Lc   6
#define DFFc 2048
#define NTOK (Bc * Sc)          // 16000

typedef __attribute__((ext_vector_type(8))) short short8;
typedef __attribute__((ext_vector_type(4))) float f32x4;

__device__ __forceinline__ float b2f(ushort u) {
    return __uint_as_float(((unsigned)u) << 16);
}
__device__ __forceinline__ ushort f2b(float f) {
    unsigned u = __float_as_uint(f);
    unsigned r = (u + 0x7fffu + ((u >> 16) & 1u)) >> 16;
    return (ushort)r;
}

#define GLL16(gp, lp) __builtin_amdgcn_global_load_lds( \
    (const __attribute__((address_space(1))) void*)(gp), \
    (__attribute__((address_space(3))) void*)(lp), 16, 0, 0)

// Property tables (PROP_TABLES constant in reference)
__constant__ float c_hydro[22]  = {1.8f,-4.5f,-3.5f,-3.5f,2.5f,-3.5f,-3.5f,-0.4f,-3.2f,4.5f,3.8f,-3.9f,1.9f,2.8f,-1.6f,-0.8f,-0.7f,-0.9f,-1.3f,4.2f,0.f,0.f};
__constant__ float c_charge[22] = {0.f,1.f,0.f,-1.f,0.f,0.f,-1.f,0.f,1.f,0.f,0.f,1.f,0.f,0.f,0.f,0.f,0.f,0.f,0.f,0.f,0.f,0.f};
__constant__ float c_vol[22]    = {88.6f,173.4f,114.1f,111.1f,108.5f,143.9f,138.4f,60.1f,153.2f,166.7f,166.7f,168.6f,162.9f,189.9f,112.7f,89.0f,116.1f,227.8f,193.6f,140.0f,0.f,100.f};

// ---------------------------------------------------------------------------
// fp32 -> bf16 cast, 4 elements/thread
// ---------------------------------------------------------------------------
__global__ __launch_bounds__(256) void castk(
    const float* __restrict__ in, ushort* __restrict__ out, int n4)
{
    const int i = blockIdx.x * 256 + threadIdx.x;
    if (i < n4) {
        const float4 v = ((const float4*)in)[i];
        ushort4 o;
        o.x = f2b(v.x); o.y = f2b(v.y); o.z = f2b(v.z); o.w = f2b(v.w);
        ((ushort4*)out)[i] = o;
    }
}

// ---------------------------------------------------------------------------
// Embedding: x[b,s,:] = concat(tok_emb, 3x prop embeds, pos_emb) + POS_ENC
// ---------------------------------------------------------------------------
__global__ __launch_bounds__(128) void embed_kernel(
    const int* __restrict__ src,
    const float* __restrict__ tok_emb,
    const float* __restrict__ pos_emb,
    const float* __restrict__ prop_W,
    const float* __restrict__ prop_b,
    float* __restrict__ X, ushort* __restrict__ X16)
{
    const int t   = blockIdx.x;
    const int s   = t % Sc;
    const int tid = threadIdx.x;
    const int tok = src[t];
    float*  xr  = X   + (size_t)t * Dc;
    ushort* xr16 = X16 + (size_t)t * Dc;
    const float NLOG = -9.210340371976184f / 640.f;
    const float pos  = (float)s;
    #pragma unroll
    for (int seg = 0; seg < 5; ++seg) {
        const int d = seg * 128 + tid;
        const float div = expf((float)(d & ~1) * NLOG);
        const float ang = pos * div;
        const float pe  = (d & 1) ? cosf(ang) : sinf(ang);
        float v;
        if      (seg == 0) v = tok_emb[tok * 128 + tid];
        else if (seg == 1) v = c_hydro[tok]  * prop_W[tid]       + prop_b[tid];
        else if (seg == 2) v = c_charge[tok] * prop_W[128 + tid] + prop_b[128 + tid];
        else if (seg == 3) v = c_vol[tok]    * prop_W[256 + tid] + prop_b[256 + tid];
        else               v = pos_emb[s * 128 + tid];
        const float r = v + pe;
        xr[d] = r;
        xr16[d] = f2b(r);
    }
}

// ---------------------------------------------------------------------------
// bf16 MFMA GEMM: C = A @ W^T + bias. 128x128 tile, BK=64 (two 32-halves per
// barrier pair -> 8 GLL16 + 32 MFMA between syncs). M%128==0, N%128==0, K%64==0.
// ---------------------------------------------------------------------------
__global__ __launch_bounds__(256) void gemm_bf16(
    const ushort* __restrict__ A, const ushort* __restrict__ W,
    const float* __restrict__ bias,
    float* __restrict__ Cf, ushort* __restrict__ Cb,
    int M, int N, int K, int relu)
{
    __shared__ ushort lA[2][4096];    // [half][128 rows x 32 cols]
    __shared__ ushort lB[2][4096];
    const int tid = threadIdx.x;
    const int wv = tid >> 6, ln = tid & 63;
    const int m0 = blockIdx.x * 128, n0 = blockIdx.y * 128;
    const int wrow = wv >> 1, wcol = wv & 1;
    const int lg = ln >> 4, lc = ln & 15;

    const int c0 = wv * 64 + ln;       // chunks: rows 0..63
    const int c1 = c0 + 256;           // rows 64..127
    const ushort* gA0 = A + (size_t)(m0 + (c0 >> 2)) * K + (c0 & 3) * 8;
    const ushort* gA1 = A + (size_t)(m0 + (c1 >> 2)) * K + (c1 & 3) * 8;
    const ushort* gB0 = W + (size_t)(n0 + (c0 >> 2)) * K + (c0 & 3) * 8;
    const ushort* gB1 = W + (size_t)(n0 + (c1 >> 2)) * K + (c1 & 3) * 8;

    f32x4 acc[4][4];
    #pragma unroll
    for (int mi = 0; mi < 4; ++mi)
        #pragma unroll
        for (int ni = 0; ni < 4; ++ni)
            acc[mi][ni] = (f32x4){0.f, 0.f, 0.f, 0.f};

    float bval[4];
    #pragma unroll
    for (int ni = 0; ni < 4; ++ni)
        bval[ni] = bias[n0 + wcol * 64 + ni * 16 + lc];

    const int foff = lc * 32 + lg * 8;     // fragment base within a half

    for (int k0 = 0; k0 < K; k0 += 64) {
        GLL16(gA0 + k0,      &lA[0][wv * 512]);
        GLL16(gA1 + k0,      &lA[0][2048 + wv * 512]);
        GLL16(gA0 + k0 + 32, &lA[1][wv * 512]);
        GLL16(gA1 + k0 + 32, &lA[1][2048 + wv * 512]);
        GLL16(gB0 + k0,      &lB[0][wv * 512]);
        GLL16(gB1 + k0,      &lB[0][2048 + wv * 512]);
        GLL16(gB0 + k0 + 32, &lB[1][wv * 512]);
        GLL16(gB1 + k0 + 32, &lB[1][2048 + wv * 512]);
        __syncthreads();            // drains vmcnt -> LDS tiles ready
        #pragma unroll
        for (int hh = 0; hh < 2; ++hh) {
            short8 af[4], bfr[4];
            #pragma unroll
            for (int mi = 0; mi < 4; ++mi)
                af[mi] = *(const short8*)&lA[hh][(wrow * 64 + mi * 16) * 32 + foff];
            #pragma unroll
            for (int ni = 0; ni < 4; ++ni)
                bfr[ni] = *(const short8*)&lB[hh][(wcol * 64 + ni * 16) * 32 + foff];
            #pragma unroll
            for (int mi = 0; mi < 4; ++mi)
                #pragma unroll
                for (int ni = 0; ni < 4; ++ni)
                    acc[mi][ni] = __builtin_amdgcn_mfma_f32_16x16x32_bf16(
                        af[mi], bfr[ni], acc[mi][ni], 0, 0, 0);
        }
        __syncthreads();            // LDS reads done before next stage
    }

    #pragma unroll
    for (int mi = 0; mi < 4; ++mi) {
        #pragma unroll
        for (int r = 0; r < 4; ++r) {
            const int m = m0 + wrow * 64 + mi * 16 + lg * 4 + r;
            #pragma unroll
            for (int ni = 0; ni < 4; ++ni) {
                const int n = n0 + wcol * 64 + ni * 16 + lc;
                float v = acc[mi][ni][r] + bval[ni];
                if (relu) v = fmaxf(v, 0.f);
                if (Cf) Cf[(size_t)m * N + n] = v;
                if (Cb) Cb[(size_t)m * N + n] = f2b(v);
            }
        }
    }
}

// ---------------------------------------------------------------------------
// MFMA flash attention, QBLK=128 (8 waves, 512 thr), KVBLK=64, T14 async-stage.
// Staging role-split: waves 0-3 stage K (row-major, dims 80..95 zeroed),
// waves 4-7 stage V transposed. Global->reg prefetch of tile t+1 issued
// before tile t's compute; reg->LDS write after the top barrier.
// Fragment maps (verified in hardware round 4): A/B row=lane&15,
// k=(lane>>4)*8+j; C/D col=lane&15, row=(lane>>4)*4+reg.
// P_lds is strictly per-wave: ds_write -> ds_read same wave, DS pipe
// in-order per wave, no barrier needed. (If validation ever fails, add
// __syncthreads() before the PV loop as first suspect.)
// ---------------------------------------------------------------------------
__global__ __launch_bounds__(512, 4) void flash_attn_mfma(
    const ushort* __restrict__ qkv, ushort* __restrict__ O16)
{
    const int bh = blockIdx.y;
    const int b = bh >> 3, h = bh & 7;
    const int q0 = blockIdx.x * 128;
    const int tid = threadIdx.x;
    const int wq = tid >> 6, ln = tid & 63;
    const int lg = ln >> 4, lc = ln & 15;
    const float scale = 0.1118033988749895f;   // 1/sqrt(80)

    __shared__ ushort K_lds[64][104];      // [key][dim 0..95, pad zeroed]
    __shared__ ushort VT_lds[80][72];      // [dim][key]
    __shared__ ushort P_lds[8][16][72];    // per-wave [qrow][key]

    const size_t RS = 1920;
    const ushort* rowbase = qkv + (size_t)b * Sc * RS;

    // Q fragments (dims 80..95 read neighbor data; K_lds rows 80..95 are zero)
    short8 qf[3];
    {
        int qrow = q0 + wq * 16 + lc; if (qrow > Sc - 1) qrow = Sc - 1;
        const ushort* qp = rowbase + (size_t)qrow * RS + h * HDc + lg * 8;
        qf[0] = *(const short8*)(qp);
        qf[1] = *(const short8*)(qp + 32);
        qf[2] = *(const short8*)(qp + 64);
    }

    // staging role
    const bool sideV = tid >= 256;
    const int st = tid & 255;
    const int sr = st >> 2, sq4 = st & 3;     // key-row 0..63, 20-dim chunk
    const size_t chunk_off = (sideV ? 2 * (size_t)Dc : (size_t)Dc) + h * HDc + sq4 * 20;
    ushort4 hold[5];

    {   // prologue: load tile 0 into regs
        int krow = sr; if (krow > Sc - 1) krow = Sc - 1;
        const ushort* p = rowbase + (size_t)krow * RS + chunk_off;
        #pragma unroll
        for (int i = 0; i < 5; ++i) hold[i] = *(const ushort4*)(p + i * 4);
    }

    float m_r[4], l_r[4];
    f32x4 o_acc[5];
    #pragma unroll
    for (int r = 0; r < 4; ++r) { m_r[r] = -1e30f; l_r[r] = 0.f; }
    #pragma unroll
    for (int dt = 0; dt < 5; ++dt) o_acc[dt] = (f32x4){0.f, 0.f, 0.f, 0.f};

    for (int kt = 0; kt < 16; ++kt) {
        const int kb = kt * 64;
        __syncthreads();                       // prior tile's LDS reads done
        if (!sideV) {                          // write staged K
            #pragma unroll
            for (int i = 0; i < 5; ++i)
                *(ushort4*)&K_lds[sr][sq4 * 20 + i * 4] = hold[i];
            ushort4 z; z.x = 0; z.y = 0; z.z = 0; z.w = 0;
            *(ushort4*)&K_lds[sr][80 + sq4 * 4] = z;
        } else {                               // write staged V (transposed)
            #pragma unroll
            for (int i = 0; i < 5; ++i) {
                const int d0 = sq4 * 20 + i * 4;
                VT_lds[d0 + 0][sr] = hold[i].x; VT_lds[d0 + 1][sr] = hold[i].y;
                VT_lds[d0 + 2][sr] = hold[i].z; VT_lds[d0 + 3][sr] = hold[i].w;
            }
        }
        __syncthreads();                       // staging visible

        if (kt < 15) {                         // T14: prefetch next tile -> regs
            int krow = kb + 64 + sr; if (krow > Sc - 1) krow = Sc - 1;
            const ushort* p = rowbase + (size_t)krow * RS + chunk_off;
            #pragma unroll
            for (int i = 0; i < 5; ++i) hold[i] = *(const ushort4*)(p + i * 4);
        }

        // ---- S = scale * Q K^T  (16 x 64 per wave) ----
        f32x4 s_acc[4];
        #pragma unroll
        for (int nt = 0; nt < 4; ++nt) s_acc[nt] = (f32x4){0.f, 0.f, 0.f, 0.f};
        __builtin_amdgcn_s_setprio(1);
        #pragma unroll
        for (int kk = 0; kk < 3; ++kk) {
            #pragma unroll
            for (int nt = 0; nt < 4; ++nt) {
                const short8 kf = *(const short8*)&K_lds[nt * 16 + lc][kk * 32 + lg * 8];
                s_acc[nt] = __builtin_amdgcn_mfma_f32_16x16x32_bf16(
                    qf[kk], kf, s_acc[nt], 0, 0, 0);
            }
        }
        __builtin_amdgcn_s_setprio(0);

        // ---- online softmax (row = lg*4 + r, key = kb + nt*16 + lc) ----
        #pragma unroll
        for (int r = 0; r < 4; ++r) {
            float mx = -1e30f;
            #pragma unroll
            for (int nt = 0; nt < 4; ++nt) {
                float s = s_acc[nt][r] * scale;
                if (kb + nt * 16 + lc >= Sc) s = -1e30f;
                s_acc[nt][r] = s;
                mx = fmaxf(mx, s);
            }
            #pragma unroll
            for (int mk = 1; mk < 16; mk <<= 1)
                mx = fmaxf(mx, __shfl_xor(mx, mk));
            const float m_new = fmaxf(m_r[r], mx);
            const float alpha = __expf(m_r[r] - m_new);
            float ps = 0.f;
            #pragma unroll
            for (int nt = 0; nt < 4; ++nt) {
                const float e = __expf(s_acc[nt][r] - m_new);
                s_acc[nt][r] = e;
                ps += e;
            }
            #pragma unroll
            for (int mk = 1; mk < 16; mk <<= 1) ps += __shfl_xor(ps, mk);
            l_r[r] = l_r[r] * alpha + ps;
            m_r[r] = m_new;
            #pragma unroll
            for (int dt = 0; dt < 5; ++dt) o_acc[dt][r] *= alpha;
        }

        // ---- P (C-layout) -> P_lds (wave-local; DS pipe in-order per wave) ----
        #pragma unroll
        for (int nt = 0; nt < 4; ++nt)
            #pragma unroll
            for (int r = 0; r < 4; ++r)
                P_lds[wq][lg * 4 + r][nt * 16 + lc] = f2b(s_acc[nt][r]);

        // ---- O += P V  (16 x 80 per wave) ----
        __builtin_amdgcn_s_setprio(1);
        #pragma unroll
        for (int kk2 = 0; kk2 < 2; ++kk2) {
            const short8 pa = *(const short8*)&P_lds[wq][lc][kk2 * 32 + lg * 8];
            #pragma unroll
            for (int dt = 0; dt < 5; ++dt) {
                const short8 vf = *(const short8*)&VT_lds[dt * 16 + lc][kk2 * 32 + lg * 8];
                o_acc[dt] = __builtin_amdgcn_mfma_f32_16x16x32_bf16(
                    pa, vf, o_acc[dt], 0, 0, 0);
            }
        }
        __builtin_amdgcn_s_setprio(0);
    }

    // ---- normalize + store ----
    #pragma unroll
    for (int r = 0; r < 4; ++r) {
        const int row = q0 + wq * 16 + lg * 4 + r;
        if (row < Sc) {
            const float inv = 1.f / l_r[r];
            ushort* op = O16 + (size_t)(b * Sc + row) * Dc + h * HDc;
            #pragma unroll
            for (int dt = 0; dt < 5; ++dt)
                op[dt * 16 + lc] = f2b(o_acc[dt][r] * inv);
        }
    }
}

// ---------------------------------------------------------------------------
// x = LN(x + y) * g + b  (fp32, row=640), bf16 shadow write. float4 path.
// ---------------------------------------------------------------------------
__global__ __launch_bounds__(256) void add_ln(
    float* __restrict__ x, const float* __restrict__ y,
    const float* __restrict__ gamma, const float* __restrict__ beta,
    ushort* __restrict__ x16)
{
    const int row = blockIdx.x;
    float4* xr = (float4*)(x + (size_t)row * Dc);            // 160 float4
    const float4* yr = (const float4*)(y + (size_t)row * Dc);
    const int tid = threadIdx.x;
    float4 v = make_float4(0.f, 0.f, 0.f, 0.f);
    if (tid < 160) {
        const float4 a = xr[tid];
        const float4 b = yr[tid];
        v.x = a.x + b.x; v.y = a.y + b.y; v.z = a.z + b.z; v.w = a.w + b.w;
    }
    float s  = v.x + v.y + v.z + v.w;
    float ss = v.x * v.x + v.y * v.y + v.z * v.z + v.w * v.w;
    #pragma unroll
    for (int mm = 1; mm < 64; mm <<= 1) {
        s  += __shfl_xor(s, mm);
        ss += __shfl_xor(ss, mm);
    }
    __shared__ float sb[4], ssb[4];
    const int w = tid >> 6;
    if ((tid & 63) == 0) { sb[w] = s; ssb[w] = ss; }
    __syncthreads();
    s  = sb[0] + sb[1] + sb[2] + sb[3];
    ss = ssb[0] + ssb[1] + ssb[2] + ssb[3];
    const float mean = s * (1.f / 640.f);
    const float var  = ss * (1.f / 640.f) - mean * mean;
    const float inv  = rsqrtf(var + 1e-5f);
    if (tid < 160) {
        const float4 g  = ((const float4*)gamma)[tid];
        const float4 be = ((const float4*)beta)[tid];
        float4 r;
        r.x = (v.x - mean) * inv * g.x + be.x;
        r.y = (v.y - mean) * inv * g.y + be.y;
        r.z = (v.z - mean) * inv * g.z + be.z;
        r.w = (v.w - mean) * inv * g.w + be.w;
        xr[tid] = r;
        ushort4 o;
        o.x = f2b(r.x); o.y = f2b(r.y); o.z = f2b(r.z); o.w = f2b(r.w);
        ((ushort4*)(x16 + (size_t)row * Dc))[tid] = o;
    }
}

// ---------------------------------------------------------------------------
// seq_rep = mean over S, two stages
// ---------------------------------------------------------------------------
__global__ __launch_bounds__(256) void seq_partial(
    const float* __restrict__ X, float* __restrict__ part)
{
    const int b = blockIdx.x, c = blockIdx.y;   // c in [0,10)
    const float* base = X + ((size_t)b * Sc + c * 100) * Dc;
    const int tid = threadIdx.x;
    float a0 = 0.f, a1 = 0.f, a2 = 0.f;
    for (int s = 0; s < 100; ++s) {
        const float* row = base + (size_t)s * Dc;
        a0 += row[tid];
        a1 += row[tid + 256];
        if (tid < 128) a2 += row[tid + 512];
    }
    float* p = part + (size_t)(b * 10 + c) * Dc;
    p[tid] = a0; p[tid + 256] = a1;
    if (tid < 128) p[tid + 512] = a2;
}

__global__ __launch_bounds__(256) void seq_final(
    const float* __restrict__ part, float* __restrict__ seq)
{
    const int b = blockIdx.x, tid = threadIdx.x;
    for (int d = tid; d < Dc; d += 256) {
        float s = 0.f;
        for (int c = 0; c < 10; ++c) s += part[(size_t)(b * 10 + c) * Dc + d];
        seq[b * Dc + d] = s * (1.f / 1000.f);
    }
}

// ---------------------------------------------------------------------------
// Head FC: C[16][N] = act(A[16][K] @ W[N][K]^T + bias). G lanes per output
// row (G=32 or 16), EPB = 256/G outputs per block. A staged in LDS (<=40KB),
// coalesced float4 weight loads, butterfly reduce within the G-group.
// dual: effective weight = w[k] + w[672+k] (the [seq,0,seq] concat trick).
// Requires K % (4*G) == 0.
// ---------------------------------------------------------------------------
template<int G>
__global__ __launch_bounds__(256) void head_fc(
    const float* __restrict__ A, const float* __restrict__ W,
    const float* __restrict__ bias, float* __restrict__ C,
    int N, int K, int ldw, int dual, int relu)
{
    __shared__ float As[10240];           // 16 x K (K <= 640)
    const int tid = threadIdx.x;
    const int el = tid / G, kg = tid % G;
    const int e = blockIdx.x * (256 / G) + el;

    const int ktot = 16 * K;
    for (int i = tid * 4; i < ktot; i += 1024)
        *(float4*)&As[i] = *(const float4*)&A[i];
    __syncthreads();

    const int kper = K / G;               // multiple of 4
    const int k0 = kg * kper;
    const float* wr = W + (size_t)e * ldw + k0;

    float acc[16];
    #pragma unroll
    for (int b2 = 0; b2 < 16; ++b2) acc[b2] = 0.f;

    for (int kk = 0; kk < kper; kk += 4) {
        float4 w4 = *(const float4*)(wr + kk);
        if (dual) {
            const float4 w2 = *(const float4*)(wr + 672 + kk);
            w4.x += w2.x; w4.y += w2.y; w4.z += w2.z; w4.w += w2.w;
        }
        #pragma unroll
        for (int b2 = 0; b2 < 16; ++b2) {
            const float4 a4 = *(const float4*)&As[b2 * K + k0 + kk];
            acc[b2] = fmaf(a4.x, w4.x, fmaf(a4.y, w4.y,
                      fmaf(a4.z, w4.z, fmaf(a4.w, w4.w, acc[b2]))));
        }
    }

    #pragma unroll
    for (int m = 1; m < G; m <<= 1)
        #pragma unroll
        for (int b2 = 0; b2 < 16; ++b2)
            acc[b2] += __shfl_xor(acc[b2], m);

    if (kg < 16) {
        float r = 0.f;
        #pragma unroll
        for (int b2 = 0; b2 < 16; ++b2)
            if (kg == b2) r = acc[b2];
        r += bias[e];
        if (relu) r = fmaxf(r, 0.f);
        C[kg * N + e] = r;
    }
}

// out[b] = dot(h3[b], rW2) + rb2
__global__ __launch_bounds__(256) void head_out(
    const float* __restrict__ h3, const float* __restrict__ rW2,
    const float* __restrict__ rb2, float* __restrict__ out)
{
    const int b = blockIdx.x, tid = threadIdx.x;
    float v = (tid < 160) ? h3[b * 160 + tid] * rW2[tid] : 0.f;
    #pragma unroll
    for (int m = 1; m < 64; m <<= 1) v += __shfl_xor(v, m);
    __shared__ float sb[4];
    if ((tid & 63) == 0) sb[tid >> 6] = v;
    __syncthreads();
    if (tid == 0) out[b] = sb[0] + sb[1] + sb[2] + sb[3] + rb2[0];
}

// ---------------------------------------------------------------------------
extern "C" void kernel_launch(void* const* d_in, const int* in_sizes, int n_in,
                              void* d_out, int out_size, void* d_ws, size_t ws_size,
                              hipStream_t stream)
{
    const int*   src     = (const int*)  d_in[0];
    const float* tok_emb = (const float*)d_in[1];
    const float* pos_emb = (const float*)d_in[2];
    const float* prop_W  = (const float*)d_in[3];
    const float* prop_b  = (const float*)d_in[4];
    const float* Wqkv    = (const float*)d_in[5];
    const float* bqkv    = (const float*)d_in[6];
    const float* Wo      = (const float*)d_in[7];
    const float* bo      = (const float*)d_in[8];
    const float* W1      = (const float*)d_in[9];
    const float* b1      = (const float*)d_in[10];
    const float* W2      = (const float*)d_in[11];
    const float* b2      = (const float*)d_in[12];
    const float* ln1_g   = (const float*)d_in[13];
    const float* ln1_b   = (const float*)d_in[14];
    const float* ln2_g   = (const float*)d_in[15];
    const float* ln2_b   = (const float*)d_in[16];
    const float* fW1     = (const float*)d_in[17];
    const float* fb1     = (const float*)d_in[18];
    const float* fW2     = (const float*)d_in[19];
    const float* fb2     = (const float*)d_in[20];
    const float* rW1     = (const float*)d_in[21];
    const float* rb1     = (const float*)d_in[22];
    const float* rW2     = (const float*)d_in[23];
    const float* rb2     = (const float*)d_in[24];
    float* out = (float*)d_out;

    // workspace layout (f32 units), total ~240 MiB
    float* ws    = (float*)d_ws;
    float*  X     = ws;                        // 10,240,000
    ushort* X16   = (ushort*)(X + 10240000);   //  5,120,000 f32 slots
    float*  R1    = X + 10240000 + 5120000;    // 16,384,000 (QKV16 / FF16 arena)
    ushort* R1u   = (ushort*)R1;
    ushort* OB16  = (ushort*)(R1 + 16384000);  //  5,120,000 f32 slots
    float*  OPROJ = R1 + 16384000 + 5120000;   // 10,240,000
    ushort* W16   = (ushort*)(OPROJ + 10240000); // 12,779,520 f32 slots
    float*  PART  = OPROJ + 10240000 + 12779520; // 102,400
    float*  SEQ   = PART + 102400;               // 10,240
    float*  HT1   = SEQ + 10240;                 // 10,240 (16x640)
    float*  HT2   = HT1 + 10240;                 //  5,120 (16x320)
    float*  HT3   = HT2 + 5120;                  //  2,560 (16x160)

    // bf16 weight arenas (ushort offsets inside W16)
    ushort* Wqkv16 = W16;                 // 6*1920*640 = 7,372,800
    ushort* Wo16   = W16 + 7372800;       // 6*640*640  = 2,457,600
    ushort* W116   = W16 + 9830400;       // 6*2048*640 = 7,864,320
    ushort* W216   = W16 + 17694720;      // 6*640*2048 = 7,864,320

    // convert weights to bf16 (once per launch)
    castk<<<7200, 256, 0, stream>>>(Wqkv, Wqkv16, 1843200);
    castk<<<2400, 256, 0, stream>>>(Wo,   Wo16,    614400);
    castk<<<7680, 256, 0, stream>>>(W1,   W116,   1966080);
    castk<<<7680, 256, 0, stream>>>(W2,   W216,   1966080);

    embed_kernel<<<NTOK, 128, 0, stream>>>(src, tok_emb, pos_emb, prop_W, prop_b, X, X16);

    for (int l = 0; l < Lc; ++l) {
        // qkv (bf16 out) : [16000 x 1920]
        gemm_bf16<<<dim3(125, 15), 256, 0, stream>>>(
            X16, Wqkv16 + (size_t)l * 1228800, bqkv + (size_t)l * 1920,
            nullptr, R1u, NTOK, 1920, 640, 0);
        // attention -> OB16 (bf16)
        flash_attn_mfma<<<dim3(8, 128), 512, 0, stream>>>(R1u, OB16);
        // o-proj -> OPROJ (f32)
        gemm_bf16<<<dim3(125, 5), 256, 0, stream>>>(
            OB16, Wo16 + (size_t)l * 409600, bo + (size_t)l * 640,
            OPROJ, nullptr, NTOK, 640, 640, 0);
        // x = LN(x + o); emit bf16 shadow
        add_ln<<<NTOK, 256, 0, stream>>>(X, OPROJ, ln1_g + l * 640, ln1_b + l * 640, X16);
        // ff1 = relu(x @ W1^T + b1) -> bf16 only [16000 x 2048]
        gemm_bf16<<<dim3(125, 16), 256, 0, stream>>>(
            X16, W116 + (size_t)l * 1310720, b1 + (size_t)l * 2048,
            nullptr, R1u, NTOK, 2048, 640, 1);
        // ff2 -> OPROJ (f32)
        gemm_bf16<<<dim3(125, 5), 256, 0, stream>>>(
            R1u, W216 + (size_t)l * 1310720, b2 + (size_t)l * 640,
            OPROJ, nullptr, NTOK, 640, 2048, 0);
        // x = LN(x + ff); emit bf16 shadow
        add_ln<<<NTOK, 256, 0, stream>>>(X, OPROJ, ln2_g + l * 640, ln2_b + l * 640, X16);
    }

    seq_partial<<<dim3(16, 10), 256, 0, stream>>>(X, PART);
    seq_final<<<16, 256, 0, stream>>>(PART, SEQ);

    // head MLP: h1 = relu(seq @ (fW1[:,0:640]+fW1[:,672:1312])^T + fb1)
    head_fc<32><<<80, 256, 0, stream>>>(SEQ, fW1, fb1, HT1, 640, 640, 1312, 1, 1);
    // h2 = h1 @ fW2^T + fb2
    head_fc<32><<<40, 256, 0, stream>>>(HT1, fW2, fb2, HT2, 320, 640, 640, 0, 0);
    // h3 = relu(h2 @ rW1^T + rb1)
    head_fc<16><<<10, 256, 0, stream>>>(HT2, rW1, rb1, HT3, 160, 320, 320, 0, 1);
    // out = h3 @ rW2^T + rb2
    head_out<<<16, 256, 0, stream>>>(HT3, rW2, rb2, out);
}

// Round 10
// 2468.508 us; speedup vs baseline: 1.2578x; 1.0697x over previous
//
#include <hip/hip_runtime.h>
#include <math.h>

// Problem constants
#define Bc   16
#define Sc   1000
#define Dc   640
#define EMBc 128
#define Hc   8
#define HDc  80
#define Lc   6
#define DFFc 2048
#define NTOK (Bc * Sc)          // 16000

typedef __attribute__((ext_vector_type(8))) short short8;
typedef __attribute__((ext_vector_type(4))) float f32x4;

__device__ __forceinline__ float b2f(ushort u) {
    return __uint_as_float(((unsigned)u) << 16);
}
__device__ __forceinline__ ushort f2b(float f) {
    unsigned u = __float_as_uint(f);
    unsigned r = (u + 0x7fffu + ((u >> 16) & 1u)) >> 16;
    return (ushort)r;
}

#define GLL16(gp, lp) __builtin_amdgcn_global_load_lds( \
    (const __attribute__((address_space(1))) void*)(gp), \
    (__attribute__((address_space(3))) void*)(lp), 16, 0, 0)

// Property tables (PROP_TABLES constant in reference)
__constant__ float c_hydro[22]  = {1.8f,-4.5f,-3.5f,-3.5f,2.5f,-3.5f,-3.5f,-0.4f,-3.2f,4.5f,3.8f,-3.9f,1.9f,2.8f,-1.6f,-0.8f,-0.7f,-0.9f,-1.3f,4.2f,0.f,0.f};
__constant__ float c_charge[22] = {0.f,1.f,0.f,-1.f,0.f,0.f,-1.f,0.f,1.f,0.f,0.f,1.f,0.f,0.f,0.f,0.f,0.f,0.f,0.f,0.f,0.f,0.f};
__constant__ float c_vol[22]    = {88.6f,173.4f,114.1f,111.1f,108.5f,143.9f,138.4f,60.1f,153.2f,166.7f,166.7f,168.6f,162.9f,189.9f,112.7f,89.0f,116.1f,227.8f,193.6f,140.0f,0.f,100.f};

// ---------------------------------------------------------------------------
// fp32 -> bf16 cast, 4 elements/thread
// ---------------------------------------------------------------------------
__global__ __launch_bounds__(256) void castk(
    const float* __restrict__ in, ushort* __restrict__ out, int n4)
{
    const int i = blockIdx.x * 256 + threadIdx.x;
    if (i < n4) {
        const float4 v = ((const float4*)in)[i];
        ushort4 o;
        o.x = f2b(v.x); o.y = f2b(v.y); o.z = f2b(v.z); o.w = f2b(v.w);
        ((ushort4*)out)[i] = o;
    }
}

// ---------------------------------------------------------------------------
// Embedding: x[b,s,:] = concat(tok_emb, 3x prop embeds, pos_emb) + POS_ENC
// ---------------------------------------------------------------------------
__global__ __launch_bounds__(128) void embed_kernel(
    const int* __restrict__ src,
    const float* __restrict__ tok_emb,
    const float* __restrict__ pos_emb,
    const float* __restrict__ prop_W,
    const float* __restrict__ prop_b,
    float* __restrict__ X, ushort* __restrict__ X16)
{
    const int t   = blockIdx.x;
    const int s   = t % Sc;
    const int tid = threadIdx.x;
    const int tok = src[t];
    float*  xr  = X   + (size_t)t * Dc;
    ushort* xr16 = X16 + (size_t)t * Dc;
    const float NLOG = -9.210340371976184f / 640.f;
    const float pos  = (float)s;
    #pragma unroll
    for (int seg = 0; seg < 5; ++seg) {
        const int d = seg * 128 + tid;
        const float div = expf((float)(d & ~1) * NLOG);
        const float ang = pos * div;
        const float pe  = (d & 1) ? cosf(ang) : sinf(ang);
        float v;
        if      (seg == 0) v = tok_emb[tok * 128 + tid];
        else if (seg == 1) v = c_hydro[tok]  * prop_W[tid]       + prop_b[tid];
        else if (seg == 2) v = c_charge[tok] * prop_W[128 + tid] + prop_b[128 + tid];
        else if (seg == 3) v = c_vol[tok]    * prop_W[256 + tid] + prop_b[256 + tid];
        else               v = pos_emb[s * 128 + tid];
        const float r = v + pe;
        xr[d] = r;
        xr16[d] = f2b(r);
    }
}

// ---------------------------------------------------------------------------
// bf16 MFMA GEMM: C = A @ W^T + bias. 128x128 tile, BK=64 (two 32-halves per
// barrier pair -> 8 GLL16 + 32 MFMA between syncs). M%128==0, N%128==0, K%64==0.
// ---------------------------------------------------------------------------
__global__ __launch_bounds__(256) void gemm_bf16(
    const ushort* __restrict__ A, const ushort* __restrict__ W,
    const float* __restrict__ bias,
    float* __restrict__ Cf, ushort* __restrict__ Cb,
    int M, int N, int K, int relu)
{
    __shared__ ushort lA[2][4096];    // [half][128 rows x 32 cols]
    __shared__ ushort lB[2][4096];
    const int tid = threadIdx.x;
    const int wv = tid >> 6, ln = tid & 63;
    const int m0 = blockIdx.x * 128, n0 = blockIdx.y * 128;
    const int wrow = wv >> 1, wcol = wv & 1;
    const int lg = ln >> 4, lc = ln & 15;

    const int c0 = wv * 64 + ln;       // chunks: rows 0..63
    const int c1 = c0 + 256;           // rows 64..127
    const ushort* gA0 = A + (size_t)(m0 + (c0 >> 2)) * K + (c0 & 3) * 8;
    const ushort* gA1 = A + (size_t)(m0 + (c1 >> 2)) * K + (c1 & 3) * 8;
    const ushort* gB0 = W + (size_t)(n0 + (c0 >> 2)) * K + (c0 & 3) * 8;
    const ushort* gB1 = W + (size_t)(n0 + (c1 >> 2)) * K + (c1 & 3) * 8;

    f32x4 acc[4][4];
    #pragma unroll
    for (int mi = 0; mi < 4; ++mi)
        #pragma unroll
        for (int ni = 0; ni < 4; ++ni)
            acc[mi][ni] = (f32x4){0.f, 0.f, 0.f, 0.f};

    float bval[4];
    #pragma unroll
    for (int ni = 0; ni < 4; ++ni)
        bval[ni] = bias[n0 + wcol * 64 + ni * 16 + lc];

    const int foff = lc * 32 + lg * 8;     // fragment base within a half

    for (int k0 = 0; k0 < K; k0 += 64) {
        GLL16(gA0 + k0,      &lA[0][wv * 512]);
        GLL16(gA1 + k0,      &lA[0][2048 + wv * 512]);
        GLL16(gA0 + k0 + 32, &lA[1][wv * 512]);
        GLL16(gA1 + k0 + 32, &lA[1][2048 + wv * 512]);
        GLL16(gB0 + k0,      &lB[0][wv * 512]);
        GLL16(gB1 + k0,      &lB[0][2048 + wv * 512]);
        GLL16(gB0 + k0 + 32, &lB[1][wv * 512]);
        GLL16(gB1 + k0 + 32, &lB[1][2048 + wv * 512]);
        __syncthreads();            // drains vmcnt -> LDS tiles ready
        #pragma unroll
        for (int hh = 0; hh < 2; ++hh) {
            short8 af[4], bfr[4];
            #pragma unroll
            for (int mi = 0; mi < 4; ++mi)
                af[mi] = *(const short8*)&lA[hh][(wrow * 64 + mi * 16) * 32 + foff];
            #pragma unroll
            for (int ni = 0; ni < 4; ++ni)
                bfr[ni] = *(const short8*)&lB[hh][(wcol * 64 + ni * 16) * 32 + foff];
            #pragma unroll
            for (int mi = 0; mi < 4; ++mi)
                #pragma unroll
                for (int ni = 0; ni < 4; ++ni)
                    acc[mi][ni] = __builtin_amdgcn_mfma_f32_16x16x32_bf16(
                        af[mi], bfr[ni], acc[mi][ni], 0, 0, 0);
        }
        __syncthreads();            // LDS reads done before next stage
    }

    #pragma unroll
    for (int mi = 0; mi < 4; ++mi) {
        #pragma unroll
        for (int r = 0; r < 4; ++r) {
            const int m = m0 + wrow * 64 + mi * 16 + lg * 4 + r;
            #pragma unroll
            for (int ni = 0; ni < 4; ++ni) {
                const int n = n0 + wcol * 64 + ni * 16 + lc;
                float v = acc[mi][ni][r] + bval[ni];
                if (relu) v = fmaxf(v, 0.f);
                if (Cf) Cf[(size_t)m * N + n] = v;
                if (Cb) Cb[(size_t)m * N + n] = f2b(v);
            }
        }
    }
}

// ---------------------------------------------------------------------------
// MFMA flash attention, QBLK=128 (8 waves, 512 thr), KVBLK=64, T14 async-stage.
// Softmax rework (round 8, desk-verified round 9):
//  - deferred-l: l_r is a PER-LANE partial (row-uniform rescale commutes with
//    the cross-lane sum); 16-lane reduction hoisted to after the tile loop.
//  - T13 defer-max (THR=8) with __ballot fast path: full shfl-max + rescale
//    only when some lane's local max exceeds m_r + 8.
//  - tail key-mask applied only at kt==15 (uniform branch).
// Fragment maps (HW-validated round 4): A/B row=lane&15, k=(lane>>4)*8+j;
// C/D col=lane&15, row=(lane>>4)*4+reg.
// ---------------------------------------------------------------------------
__global__ __launch_bounds__(512, 4) void flash_attn_mfma(
    const ushort* __restrict__ qkv, ushort* __restrict__ O16)
{
    const int bh = blockIdx.y;
    const int b = bh >> 3, h = bh & 7;
    const int q0 = blockIdx.x * 128;
    const int tid = threadIdx.x;
    const int wq = tid >> 6, ln = tid & 63;
    const int lg = ln >> 4, lc = ln & 15;
    const float scale = 0.1118033988749895f;   // 1/sqrt(80)

    __shared__ ushort K_lds[64][104];      // [key][dim 0..95, pad zeroed]
    __shared__ ushort VT_lds[80][72];      // [dim][key]
    __shared__ ushort P_lds[8][16][72];    // per-wave [qrow][key]

    const size_t RS = 1920;
    const ushort* rowbase = qkv + (size_t)b * Sc * RS;

    // Q fragments (dims 80..95 read neighbor data; K_lds rows 80..95 are zero)
    short8 qf[3];
    {
        int qrow = q0 + wq * 16 + lc; if (qrow > Sc - 1) qrow = Sc - 1;
        const ushort* qp = rowbase + (size_t)qrow * RS + h * HDc + lg * 8;
        qf[0] = *(const short8*)(qp);
        qf[1] = *(const short8*)(qp + 32);
        qf[2] = *(const short8*)(qp + 64);
    }

    // staging role
    const bool sideV = tid >= 256;
    const int st = tid & 255;
    const int sr = st >> 2, sq4 = st & 3;     // key-row 0..63, 20-dim chunk
    const size_t chunk_off = (sideV ? 2 * (size_t)Dc : (size_t)Dc) + h * HDc + sq4 * 20;
    ushort4 hold[5];

    {   // prologue: load tile 0 into regs
        int krow = sr; if (krow > Sc - 1) krow = Sc - 1;
        const ushort* p = rowbase + (size_t)krow * RS + chunk_off;
        #pragma unroll
        for (int i = 0; i < 5; ++i) hold[i] = *(const ushort4*)(p + i * 4);
    }

    float m_r[4], l_r[4];
    f32x4 o_acc[5];
    #pragma unroll
    for (int r = 0; r < 4; ++r) { m_r[r] = -1e30f; l_r[r] = 0.f; }
    #pragma unroll
    for (int dt = 0; dt < 5; ++dt) o_acc[dt] = (f32x4){0.f, 0.f, 0.f, 0.f};

    for (int kt = 0; kt < 16; ++kt) {
        __syncthreads();                       // prior tile's LDS reads done
        if (!sideV) {                          // write staged K
            #pragma unroll
            for (int i = 0; i < 5; ++i)
                *(ushort4*)&K_lds[sr][sq4 * 20 + i * 4] = hold[i];
            ushort4 z; z.x = 0; z.y = 0; z.z = 0; z.w = 0;
            *(ushort4*)&K_lds[sr][80 + sq4 * 4] = z;
        } else {                               // write staged V (transposed)
            #pragma unroll
            for (int i = 0; i < 5; ++i) {
                const int d0 = sq4 * 20 + i * 4;
                VT_lds[d0 + 0][sr] = hold[i].x; VT_lds[d0 + 1][sr] = hold[i].y;
                VT_lds[d0 + 2][sr] = hold[i].z; VT_lds[d0 + 3][sr] = hold[i].w;
            }
        }
        __syncthreads();                       // staging visible

        if (kt < 15) {                         // T14: prefetch next tile -> regs
            int krow = kt * 64 + 64 + sr; if (krow > Sc - 1) krow = Sc - 1;
            const ushort* p = rowbase + (size_t)krow * RS + chunk_off;
            #pragma unroll
            for (int i = 0; i < 5; ++i) hold[i] = *(const ushort4*)(p + i * 4);
        }

        // ---- S = Q K^T (unscaled; scale folded into the exp fma) ----
        f32x4 s_acc[4];
        #pragma unroll
        for (int nt = 0; nt < 4; ++nt) s_acc[nt] = (f32x4){0.f, 0.f, 0.f, 0.f};
        __builtin_amdgcn_s_setprio(1);
        #pragma unroll
        for (int kk = 0; kk < 3; ++kk) {
            #pragma unroll
            for (int nt = 0; nt < 4; ++nt) {
                const short8 kf = *(const short8*)&K_lds[nt * 16 + lc][kk * 32 + lg * 8];
                s_acc[nt] = __builtin_amdgcn_mfma_f32_16x16x32_bf16(
                    qf[kk], kf, s_acc[nt], 0, 0, 0);
            }
        }
        __builtin_amdgcn_s_setprio(0);

        // ---- tail mask (uniform branch; only kt==15 has keys >= Sc) ----
        if (kt == 15) {
            #pragma unroll
            for (int r = 0; r < 4; ++r) {
                s_acc[3][r] = -1e30f;              // keys 1008..1023
                if (lc >= 8) s_acc[2][r] = -1e30f; // keys 1000..1007
            }
        }

        // ---- online softmax: defer-max + per-lane partial l ----
        #pragma unroll
        for (int r = 0; r < 4; ++r) {
            const float mloc = fmaxf(fmaxf(s_acc[0][r], s_acc[1][r]),
                                     fmaxf(s_acc[2][r], s_acc[3][r])) * scale;
            const unsigned long long vote = __ballot(mloc > m_r[r] + 8.f);
            if ((vote >> (lg * 16)) & 0xFFFFull) {   // uniform within row group
                float mx = mloc;
                #pragma unroll
                for (int mk = 1; mk < 16; mk <<= 1)
                    mx = fmaxf(mx, __shfl_xor(mx, mk));
                const float m_new = fmaxf(m_r[r], mx);
                const float alpha = __expf(m_r[r] - m_new);
                l_r[r] *= alpha;
                #pragma unroll
                for (int dt = 0; dt < 5; ++dt) o_acc[dt][r] *= alpha;
                m_r[r] = m_new;
            }
            float ps = 0.f;
            #pragma unroll
            for (int nt = 0; nt < 4; ++nt) {
                const float e = __expf(fmaf(s_acc[nt][r], scale, -m_r[r]));
                s_acc[nt][r] = e;
                ps += e;
            }
            l_r[r] += ps;                            // per-lane partial
        }

        // ---- P (C-layout) -> P_lds (wave-local; DS pipe in-order per wave) ----
        #pragma unroll
        for (int nt = 0; nt < 4; ++nt)
            #pragma unroll
            for (int r = 0; r < 4; ++r)
                P_lds[wq][lg * 4 + r][nt * 16 + lc] = f2b(s_acc[nt][r]);

        // ---- O += P V  (16 x 80 per wave) ----
        __builtin_amdgcn_s_setprio(1);
        #pragma unroll
        for (int kk2 = 0; kk2 < 2; ++kk2) {
            const short8 pa = *(const short8*)&P_lds[wq][lc][kk2 * 32 + lg * 8];
            #pragma unroll
            for (int dt = 0; dt < 5; ++dt) {
                const short8 vf = *(const short8*)&VT_lds[dt * 16 + lc][kk2 * 32 + lg * 8];
                o_acc[dt] = __builtin_amdgcn_mfma_f32_16x16x32_bf16(
                    pa, vf, o_acc[dt], 0, 0, 0);
            }
        }
        __builtin_amdgcn_s_setprio(0);
    }

    // ---- hoisted l reduction (16-lane row groups) ----
    #pragma unroll
    for (int r = 0; r < 4; ++r)
        #pragma unroll
        for (int mk = 1; mk < 16; mk <<= 1)
            l_r[r] += __shfl_xor(l_r[r], mk);

    // ---- normalize + store ----
    #pragma unroll
    for (int r = 0; r < 4; ++r) {
        const int row = q0 + wq * 16 + lg * 4 + r;
        if (row < Sc) {
            const float inv = 1.f / l_r[r];
            ushort* op = O16 + (size_t)(b * Sc + row) * Dc + h * HDc;
            #pragma unroll
            for (int dt = 0; dt < 5; ++dt)
                op[dt * 16 + lc] = f2b(o_acc[dt][r] * inv);
        }
    }
}

// ---------------------------------------------------------------------------
// x = LN(x + y) * g + b  (fp32, row=640), bf16 shadow write. float4 path.
// ---------------------------------------------------------------------------
__global__ __launch_bounds__(256) void add_ln(
    float* __restrict__ x, const float* __restrict__ y,
    const float* __restrict__ gamma, const float* __restrict__ beta,
    ushort* __restrict__ x16)
{
    const int row = blockIdx.x;
    float4* xr = (float4*)(x + (size_t)row * Dc);            // 160 float4
    const float4* yr = (const float4*)(y + (size_t)row * Dc);
    const int tid = threadIdx.x;
    float4 v = make_float4(0.f, 0.f, 0.f, 0.f);
    if (tid < 160) {
        const float4 a = xr[tid];
        const float4 b = yr[tid];
        v.x = a.x + b.x; v.y = a.y + b.y; v.z = a.z + b.z; v.w = a.w + b.w;
    }
    float s  = v.x + v.y + v.z + v.w;
    float ss = v.x * v.x + v.y * v.y + v.z * v.z + v.w * v.w;
    #pragma unroll
    for (int mm = 1; mm < 64; mm <<= 1) {
        s  += __shfl_xor(s, mm);
        ss += __shfl_xor(ss, mm);
    }
    __shared__ float sb[4], ssb[4];
    const int w = tid >> 6;
    if ((tid & 63) == 0) { sb[w] = s; ssb[w] = ss; }
    __syncthreads();
    s  = sb[0] + sb[1] + sb[2] + sb[3];
    ss = ssb[0] + ssb[1] + ssb[2] + ssb[3];
    const float mean = s * (1.f / 640.f);
    const float var  = ss * (1.f / 640.f) - mean * mean;
    const float inv  = rsqrtf(var + 1e-5f);
    if (tid < 160) {
        const float4 g  = ((const float4*)gamma)[tid];
        const float4 be = ((const float4*)beta)[tid];
        float4 r;
        r.x = (v.x - mean) * inv * g.x + be.x;
        r.y = (v.y - mean) * inv * g.y + be.y;
        r.z = (v.z - mean) * inv * g.z + be.z;
        r.w = (v.w - mean) * inv * g.w + be.w;
        xr[tid] = r;
        ushort4 o;
        o.x = f2b(r.x); o.y = f2b(r.y); o.z = f2b(r.z); o.w = f2b(r.w);
        ((ushort4*)(x16 + (size_t)row * Dc))[tid] = o;
    }
}

// ---------------------------------------------------------------------------
// seq_rep = mean over S, two stages
// ---------------------------------------------------------------------------
__global__ __launch_bounds__(256) void seq_partial(
    const float* __restrict__ X, float* __restrict__ part)
{
    const int b = blockIdx.x, c = blockIdx.y;   // c in [0,10)
    const float* base = X + ((size_t)b * Sc + c * 100) * Dc;
    const int tid = threadIdx.x;
    float a0 = 0.f, a1 = 0.f, a2 = 0.f;
    for (int s = 0; s < 100; ++s) {
        const float* row = base + (size_t)s * Dc;
        a0 += row[tid];
        a1 += row[tid + 256];
        if (tid < 128) a2 += row[tid + 512];
    }
    float* p = part + (size_t)(b * 10 + c) * Dc;
    p[tid] = a0; p[tid + 256] = a1;
    if (tid < 128) p[tid + 512] = a2;
}

__global__ __launch_bounds__(256) void seq_final(
    const float* __restrict__ part, float* __restrict__ seq)
{
    const int b = blockIdx.x, tid = threadIdx.x;
    for (int d = tid; d < Dc; d += 256) {
        float s = 0.f;
        for (int c = 0; c < 10; ++c) s += part[(size_t)(b * 10 + c) * Dc + d];
        seq[b * Dc + d] = s * (1.f / 1000.f);
    }
}

// ---------------------------------------------------------------------------
// Head FC: C[16][N] = act(A[16][K] @ W[N][K]^T + bias). G lanes per output
// row (G=32 or 16). A staged in LDS, coalesced float4 weight loads,
// butterfly reduce within the G-group. dual: w[k] + w[672+k].
// ---------------------------------------------------------------------------
template<int G>
__global__ __launch_bounds__(256) void head_fc(
    const float* __restrict__ A, const float* __restrict__ W,
    const float* __restrict__ bias, float* __restrict__ C,
    int N, int K, int ldw, int dual, int relu)
{
    __shared__ float As[10240];           // 16 x K (K <= 640)
    const int tid = threadIdx.x;
    const int el = tid / G, kg = tid % G;
    const int e = blockIdx.x * (256 / G) + el;

    const int ktot = 16 * K;
    for (int i = tid * 4; i < ktot; i += 1024)
        *(float4*)&As[i] = *(const float4*)&A[i];
    __syncthreads();

    const int kper = K / G;               // multiple of 4
    const int k0 = kg * kper;
    const float* wr = W + (size_t)e * ldw + k0;

    float acc[16];
    #pragma unroll
    for (int b2 = 0; b2 < 16; ++b2) acc[b2] = 0.f;

    for (int kk = 0; kk < kper; kk += 4) {
        float4 w4 = *(const float4*)(wr + kk);
        if (dual) {
            const float4 w2 = *(const float4*)(wr + 672 + kk);
            w4.x += w2.x; w4.y += w2.y; w4.z += w2.z; w4.w += w2.w;
        }
        #pragma unroll
        for (int b2 = 0; b2 < 16; ++b2) {
            const float4 a4 = *(const float4*)&As[b2 * K + k0 + kk];
            acc[b2] = fmaf(a4.x, w4.x, fmaf(a4.y, w4.y,
                      fmaf(a4.z, w4.z, fmaf(a4.w, w4.w, acc[b2]))));
        }
    }

    #pragma unroll
    for (int m = 1; m < G; m <<= 1)
        #pragma unroll
        for (int b2 = 0; b2 < 16; ++b2)
            acc[b2] += __shfl_xor(acc[b2], m);

    if (kg < 16) {
        float r = 0.f;
        #pragma unroll
        for (int b2 = 0; b2 < 16; ++b2)
            if (kg == b2) r = acc[b2];
        r += bias[e];
        if (relu) r = fmaxf(r, 0.f);
        C[kg * N + e] = r;
    }
}

// out[b] = dot(h3[b], rW2) + rb2
__global__ __launch_bounds__(256) void head_out(
    const float* __restrict__ h3, const float* __restrict__ rW2,
    const float* __restrict__ rb2, float* __restrict__ out)
{
    const int b = blockIdx.x, tid = threadIdx.x;
    float v = (tid < 160) ? h3[b * 160 + tid] * rW2[tid] : 0.f;
    #pragma unroll
    for (int m = 1; m < 64; m <<= 1) v += __shfl_xor(v, m);
    __shared__ float sb[4];
    if ((tid & 63) == 0) sb[tid >> 6] = v;
    __syncthreads();
    if (tid == 0) out[b] = sb[0] + sb[1] + sb[2] + sb[3] + rb2[0];
}

// ---------------------------------------------------------------------------
extern "C" void kernel_launch(void* const* d_in, const int* in_sizes, int n_in,
                              void* d_out, int out_size, void* d_ws, size_t ws_size,
                              hipStream_t stream)
{
    const int*   src     = (const int*)  d_in[0];
    const float* tok_emb = (const float*)d_in[1];
    const float* pos_emb = (const float*)d_in[2];
    const float* prop_W  = (const float*)d_in[3];
    const float* prop_b  = (const float*)d_in[4];
    const float* Wqkv    = (const float*)d_in[5];
    const float* bqkv    = (const float*)d_in[6];
    const float* Wo      = (const float*)d_in[7];
    const float* bo      = (const float*)d_in[8];
    const float* W1      = (const float*)d_in[9];
    const float* b1      = (const float*)d_in[10];
    const float* W2      = (const float*)d_in[11];
    const float* b2      = (const float*)d_in[12];
    const float* ln1_g   = (const float*)d_in[13];
    const float* ln1_b   = (const float*)d_in[14];
    const float* ln2_g   = (const float*)d_in[15];
    const float* ln2_b   = (const float*)d_in[16];
    const float* fW1     = (const float*)d_in[17];
    const float* fb1     = (const float*)d_in[18];
    const float* fW2     = (const float*)d_in[19];
    const float* fb2     = (const float*)d_in[20];
    const float* rW1     = (const float*)d_in[21];
    const float* rb1     = (const float*)d_in[22];
    const float* rW2     = (const float*)d_in[23];
    const float* rb2     = (const float*)d_in[24];
    float* out = (float*)d_out;

    // workspace layout (f32 units), total ~240 MiB
    float* ws    = (float*)d_ws;
    float*  X     = ws;                        // 10,240,000
    ushort* X16   = (ushort*)(X + 10240000);   //  5,120,000 f32 slots
    float*  R1    = X + 10240000 + 5120000;    // 16,384,000 (QKV16 / FF16 arena)
    ushort* R1u   = (ushort*)R1;
    ushort* OB16  = (ushort*)(R1 + 16384000);  //  5,120,000 f32 slots
    float*  OPROJ = R1 + 16384000 + 5120000;   // 10,240,000
    ushort* W16   = (ushort*)(OPROJ + 10240000); // 12,779,520 f32 slots
    float*  PART  = OPROJ + 10240000 + 12779520; // 102,400
    float*  SEQ   = PART + 102400;               // 10,240
    float*  HT1   = SEQ + 10240;                 // 10,240 (16x640)
    float*  HT2   = HT1 + 10240;                 //  5,120 (16x320)
    float*  HT3   = HT2 + 5120;                  //  2,560 (16x160)

    // bf16 weight arenas (ushort offsets inside W16)
    ushort* Wqkv16 = W16;                 // 6*1920*640 = 7,372,800
    ushort* Wo16   = W16 + 7372800;       // 6*640*640  = 2,457,600
    ushort* W116   = W16 + 9830400;       // 6*2048*640 = 7,864,320
    ushort* W216   = W16 + 17694720;      // 6*640*2048 = 7,864,320

    // convert weights to bf16 (once per launch)
    castk<<<7200, 256, 0, stream>>>(Wqkv, Wqkv16, 1843200);
    castk<<<2400, 256, 0, stream>>>(Wo,   Wo16,    614400);
    castk<<<7680, 256, 0, stream>>>(W1,   W116,   1966080);
    castk<<<7680, 256, 0, stream>>>(W2,   W216,   1966080);

    embed_kernel<<<NTOK, 128, 0, stream>>>(src, tok_emb, pos_emb, prop_W, prop_b, X, X16);

    for (int l = 0; l < Lc; ++l) {
        // qkv (bf16 out) : [16000 x 1920]
        gemm_bf16<<<dim3(125, 15), 256, 0, stream>>>(
            X16, Wqkv16 + (size_t)l * 1228800, bqkv + (size_t)l * 1920,
            nullptr, R1u, NTOK, 1920, 640, 0);
        // attention -> OB16 (bf16)
        flash_attn_mfma<<<dim3(8, 128), 512, 0, stream>>>(R1u, OB16);
        // o-proj -> OPROJ (f32)
        gemm_bf16<<<dim3(125, 5), 256, 0, stream>>>(
            OB16, Wo16 + (size_t)l * 409600, bo + (size_t)l * 640,
            OPROJ, nullptr, NTOK, 640, 640, 0);
        // x = LN(x + o); emit bf16 shadow
        add_ln<<<NTOK, 256, 0, stream>>>(X, OPROJ, ln1_g + l * 640, ln1_b + l * 640, X16);
        // ff1 = relu(x @ W1^T + b1) -> bf16 only [16000 x 2048]
        gemm_bf16<<<dim3(125, 16), 256, 0, stream>>>(
            X16, W116 + (size_t)l * 1310720, b1 + (size_t)l * 2048,
            nullptr, R1u, NTOK, 2048, 640, 1);
        // ff2 -> OPROJ (f32)
        gemm_bf16<<<dim3(125, 5), 256, 0, stream>>>(
            R1u, W216 + (size_t)l * 1310720, b2 + (size_t)l * 640,
            OPROJ, nullptr, NTOK, 640, 2048, 0);
        // x = LN(x + ff); emit bf16 shadow
        add_ln<<<NTOK, 256, 0, stream>>>(X, OPROJ, ln2_g + l * 640, ln2_b + l * 640, X16);
    }

    seq_partial<<<dim3(16, 10), 256, 0, stream>>>(X, PART);
    seq_final<<<16, 256, 0, stream>>>(PART, SEQ);

    // head MLP
    head_fc<32><<<80, 256, 0, stream>>>(SEQ, fW1, fb1, HT1, 640, 640, 1312, 1, 1);
    head_fc<32><<<40, 256, 0, stream>>>(HT1, fW2, fb2, HT2, 320, 640, 640, 0, 0);
    head_fc<16><<<10, 256, 0, stream>>>(HT2, rW1, rb1, HT3, 160, 320, 320, 0, 1);
    head_out<<<16, 256, 0, stream>>>(HT3, rW2, rb2, out);
}